// Round 5
// baseline (184.439 us; speedup 1.0000x reference)
//
#include <hip/hip_runtime.h>
#include <math.h>

#define HH 768
#define NHEADS 12
#define HDIM 64
#define SEQ 2048
#define NB 2
#define L2E 1.44269504088896f

typedef __attribute__((ext_vector_type(8))) short s8v;
typedef __attribute__((ext_vector_type(4))) short s4v;
typedef __attribute__((ext_vector_type(4))) float f4v;

static __device__ inline short f2bf(float f) {
    union { float f; unsigned u; } v; v.f = f;
    unsigned r = v.u + 0x7fff + ((v.u >> 16) & 1);   // RNE
    return (short)(r >> 16);
}

#if __has_builtin(__builtin_amdgcn_exp2f)
#define EXP2(x) __builtin_amdgcn_exp2f(x)
#else
#define EXP2(x) __expf((x) * 0.6931471805599453f)
#endif

__device__ __forceinline__ unsigned cvt_pk_bf16(float a, float b) {
    unsigned r;
    asm("v_cvt_pk_bf16_f32 %0, %1, %2" : "=v"(r) : "v"(a), "v"(b));
    return r;
}

__device__ __forceinline__ void gld16(const void* g, void* l) {
    __builtin_amdgcn_global_load_lds(
        (const __attribute__((address_space(1))) void*)g,
        (__attribute__((address_space(3))) void*)l, 16, 0, 0);
}

// ---------------------------------------------------------------------------
// fp32 -> bf16 conversion: X (4096x768) and the 4 weight matrices (768x768).
// ---------------------------------------------------------------------------
#define XV8   393216
#define WV8   73728
__global__ __launch_bounds__(256)
void cvt_kernel(const float* __restrict__ X, short* __restrict__ Xb,
                const float* __restrict__ W0, short* __restrict__ W0b,
                const float* __restrict__ W1, short* __restrict__ W1b,
                const float* __restrict__ W2, short* __restrict__ W2b,
                const float* __restrict__ W3, short* __restrict__ W3b)
{
    int gid = blockIdx.x * 256 + threadIdx.x;
    const float* src; short* dst; size_t off;
    if      (gid < XV8)            { src = X;  dst = Xb;  off = gid; }
    else if (gid < XV8 + WV8)      { src = W0; dst = W0b; off = gid - XV8; }
    else if (gid < XV8 + 2*WV8)    { src = W1; dst = W1b; off = gid - XV8 - WV8; }
    else if (gid < XV8 + 3*WV8)    { src = W2; dst = W2b; off = gid - XV8 - 2*WV8; }
    else if (gid < XV8 + 4*WV8)    { src = W3; dst = W3b; off = gid - XV8 - 3*WV8; }
    else return;
    off *= 8;
    float4 a = *(const float4*)(src + off);
    float4 b = *(const float4*)(src + off + 4);
    s8v o;
    o[0] = f2bf(a.x); o[1] = f2bf(a.y); o[2] = f2bf(a.z); o[3] = f2bf(a.w);
    o[4] = f2bf(b.x); o[5] = f2bf(b.y); o[6] = f2bf(b.z); o[7] = f2bf(b.w);
    *(s8v*)(dst + off) = o;
}

// ---------------------------------------------------------------------------
// MFMA GEMM, 128x128 tile, BK=32, 4 waves (2x2, 64x64 each).
// EPI 0: fused QKV -> bf16 [B,NH,S,HD], Q scaled by 0.125*log2(e).
// EPI 1: out-proj -> fp32 [4096,768] + bias + residual.
// ---------------------------------------------------------------------------
template<int EPI>
__global__ __launch_bounds__(256)
void gemm_mfma(const short* __restrict__ A,
               const short* __restrict__ Wq, const short* __restrict__ Wk,
               const short* __restrict__ Wv,
               const float* __restrict__ bq, const float* __restrict__ bk,
               const float* __restrict__ bv,
               short* __restrict__ Qo, short* __restrict__ Ko, short* __restrict__ Vo,
               const float* __restrict__ Xres, float* __restrict__ Fo)
{
    __shared__ __align__(16) short As[128*32];
    __shared__ __align__(16) short Bs[128*32];

    const int tid  = threadIdx.x;
    const int w    = tid >> 6;
    const int lane = tid & 63;
    const int g    = lane >> 4;
    const int r    = lane & 15;
    const int wr   = w >> 1;
    const int wc   = w & 1;
    const int m0   = blockIdx.y * 128;

    int n0;
    const short* Wb; const float* bias; short* outp; float scale;
    if (EPI == 0) {
        const int seg = blockIdx.x / 6;
        n0 = (blockIdx.x % 6) * 128;
        Wb   = seg == 0 ? Wq : seg == 1 ? Wk : Wv;
        bias = seg == 0 ? bq : seg == 1 ? bk : bv;
        outp = seg == 0 ? Qo : seg == 1 ? Ko : Vo;
        scale = seg == 0 ? (0.125f * L2E) : 1.0f;
    } else {
        n0 = blockIdx.x * 128;
        Wb = Wq; bias = bq; outp = nullptr; scale = 1.0f;
    }

    const int lrow = lane >> 2;
    const int lcol = (lane & 3) * 8;
    const short* Ag0 = A  + (size_t)(m0 + w*32 + lrow) * HH + lcol;
    const short* Bg0 = Wb + (size_t)(n0 + w*32 + lrow) * HH + lcol;
    short* Al0 = As + (w*32)      * 32;
    short* Al1 = As + (w*32 + 16) * 32;
    short* Bl0 = Bs + (w*32)      * 32;
    short* Bl1 = Bs + (w*32 + 16) * 32;

    f4v acc[4][4];
    #pragma unroll
    for (int i = 0; i < 4; i++)
        #pragma unroll
        for (int j = 0; j < 4; j++) acc[i][j] = (f4v){0.f,0.f,0.f,0.f};

    for (int kt = 0; kt < HH/32; ++kt) {
        const int k0 = kt * 32;
        gld16(Ag0 + k0,           Al0);
        gld16(Ag0 + k0 + 16*HH,   Al1);
        gld16(Bg0 + k0,           Bl0);
        gld16(Bg0 + k0 + 16*HH,   Bl1);
        __syncthreads();

        s8v af[4], bf[4];
        #pragma unroll
        for (int mi = 0; mi < 4; mi++)
            af[mi] = *(const s8v*)(As + (wr*64 + mi*16 + r)*32 + g*8);
        #pragma unroll
        for (int ni = 0; ni < 4; ni++)
            bf[ni] = *(const s8v*)(Bs + (wc*64 + ni*16 + r)*32 + g*8);
        __builtin_amdgcn_s_setprio(1);
        #pragma unroll
        for (int mi = 0; mi < 4; mi++)
            #pragma unroll
            for (int ni = 0; ni < 4; ni++)
                acc[mi][ni] = __builtin_amdgcn_mfma_f32_16x16x32_bf16(af[mi], bf[ni], acc[mi][ni], 0, 0, 0);
        __builtin_amdgcn_s_setprio(0);
        __syncthreads();
    }

    if (EPI == 0) {
        #pragma unroll
        for (int mi = 0; mi < 4; mi++) {
            #pragma unroll
            for (int j = 0; j < 4; j++) {
                const int m = m0 + wr*64 + mi*16 + 4*g + j;
                const int bb = m >> 11;
                const int s  = m & 2047;
                #pragma unroll
                for (int ni = 0; ni < 4; ni++) {
                    const int n = n0 + wc*64 + ni*16 + r;
                    const int h = n >> 6;
                    const int d = n & 63;
                    outp[((size_t)((bb*NHEADS + h)*SEQ) + s)*HDIM + d] =
                        f2bf((acc[mi][ni][j] + bias[n]) * scale);
                }
            }
        }
    } else {
        #pragma unroll
        for (int mi = 0; mi < 4; mi++) {
            #pragma unroll
            for (int j = 0; j < 4; j++) {
                const int m = m0 + wr*64 + mi*16 + 4*g + j;
                #pragma unroll
                for (int ni = 0; ni < 4; ni++) {
                    const int n = n0 + wc*64 + ni*16 + r;
                    Fo[(size_t)m*HH + n] = acc[mi][ni][j] + bias[n] + Xres[(size_t)m*HH + n];
                }
            }
        }
    }
}

// ---------------------------------------------------------------------------
// V [B,NH,S,HD] -> VT [B,NH,HD,S], 64x64 LDS tiles.
// ---------------------------------------------------------------------------
__global__ __launch_bounds__(256)
void vtrans_kernel(const short* __restrict__ V, short* __restrict__ VT)
{
    const int st = blockIdx.x;
    const int h  = blockIdx.y;
    const int b  = blockIdx.z;
    __shared__ short T[64][72];
    const int t = threadIdx.x;
    const short* src = V + ((size_t)(b*NHEADS + h)*SEQ + st*64) * HDIM;

    {
        const int sl = t >> 2;
        const int dq = (t & 3) * 16;
        s8v a = *(const s8v*)(src + sl*HDIM + dq);
        s8v c = *(const s8v*)(src + sl*HDIM + dq + 8);
        #pragma unroll
        for (int i = 0; i < 8; i++) { T[dq+i][sl] = a[i]; T[dq+8+i][sl] = c[i]; }
    }
    __syncthreads();
    {
        const int d  = t >> 2;
        const int sq = (t & 3) * 16;
        s8v o0 = *(const s8v*)&T[d][sq];
        s8v o1 = *(const s8v*)&T[d][sq+8];
        short* dst = VT + ((size_t)(b*NHEADS + h)*HDIM + d)*SEQ + st*64 + sq;
        *(s8v*)(dst)     = o0;
        *(s8v*)(dst + 8) = o1;
    }
}

// ---------------------------------------------------------------------------
// Flash attention, bf16 MFMA, 8 waves / 512 threads.
// Waves split KV tiles by parity (grp = w>>2); wave w&3 owns 16 q rows.
// Fixed-max exp2 softmax (scores bounded; shift-invariance => exact),
// per-lane deferred l-sum, partials merged via LDS at the end.
// Q pre-scaled by 0.125*log2e. K: [B,NH,S,HD]. VT: [B,NH,HD,S]. CTX: bf16.
// ---------------------------------------------------------------------------
#define NT (SEQ/64)
#define NPAIR (NT/2)
__global__ __launch_bounds__(512, 6)
void attn_mfma(const short* __restrict__ Q, const short* __restrict__ K,
               const short* __restrict__ VT, const float* __restrict__ mask,
               short* __restrict__ CTX)
{
    const int qt = blockIdx.x;
    const int h  = blockIdx.y;
    const int b  = blockIdx.z;
    const size_t hb = (size_t)(b * NHEADS + h);
    const short* Qg  = Q  + hb * SEQ * HDIM;
    const short* Kg  = K  + hb * SEQ * HDIM;
    const short* VTg = VT + hb * HDIM * SEQ;

    __shared__ __align__(16) char lds[49152];
    char* KsB = lds;              // [2][8192] K tiles (even, odd)
    char* VsB = lds + 16384;      // [2][8192] V^T tiles
    char* PsB = lds + 32768;      // [8][2048] per-wave P

    const int tid  = threadIdx.x;
    const int w    = tid >> 6;
    const int grp  = w >> 2;      // tile parity group
    const int wq   = w & 3;       // q-subtile owner
    const int lane = tid & 63;
    const int g    = lane >> 4;
    const int r    = lane & 15;
    const int q0   = qt * 64;

    const short* qrow = Qg + (size_t)(q0 + wq*16 + r) * HDIM;
    const s8v qf0 = *(const s8v*)(qrow + 8*g);
    const s8v qf1 = *(const s8v*)(qrow + 8*g + 32);

    f4v acc[4];
    #pragma unroll
    for (int t = 0; t < 4; t++) acc[t] = (f4v){0.f, 0.f, 0.f, 0.f};
    f4v lsum = (f4v){0.f, 0.f, 0.f, 0.f};

    // staging: 512 threads, 1 row per tile per matrix
    const int sr  = tid >> 3;           // 0..63
    const int sce = (tid & 7) * 8;
    const int swz = ((tid & 7) * 16) ^ ((sr & 7) << 4);
    s8v kr0, kr1, vr0, vr1;

    #define LOADP(PT) do { const int kb0 = (PT)*128;                          \
        kr0 = *(const s8v*)(Kg  + (size_t)(kb0 + sr)      * HDIM + sce);      \
        kr1 = *(const s8v*)(Kg  + (size_t)(kb0 + 64 + sr) * HDIM + sce);      \
        vr0 = *(const s8v*)(VTg + (size_t)sr * SEQ + kb0 + sce);              \
        vr1 = *(const s8v*)(VTg + (size_t)sr * SEQ + kb0 + 64 + sce);         \
    } while (0)

    #define STOREP() do {                                                     \
        *(s8v*)(KsB +        sr*128 + swz) = kr0;                             \
        *(s8v*)(KsB + 8192 + sr*128 + swz) = kr1;                             \
        *(s8v*)(VsB +        sr*128 + swz) = vr0;                             \
        *(s8v*)(VsB + 8192 + sr*128 + swz) = vr1;                             \
    } while (0)

    LOADP(0);
    STOREP();
    LOADP(1);
    __syncthreads();

    const char* Kc = KsB + grp*8192;
    const char* Vc = VsB + grp*8192;
    char* pb = PsB + w*2048;

    for (int pt = 0; pt < NPAIR; ++pt) {
        const int t  = 2*pt + grp;
        const int k0 = t * 64;

        float madd[4];
        #pragma unroll
        for (int j = 0; j < 4; j++)
            madd[j] = (mask[b*SEQ + k0 + 16*j + r] - 1.0f) * (10000.0f * L2E);

        // ---- QK^T (log2-space scores) ----
        f4v sj[4];
        __builtin_amdgcn_s_setprio(1);
        #pragma unroll
        for (int j = 0; j < 4; j++) {
            const int krow = 16*j + r;
            const char* kb = Kc + krow * 128;
            const int sw = (krow & 7) << 4;
            s8v kf0 = *(const s8v*)(kb + ((16*g)      ^ sw));
            s8v kf1 = *(const s8v*)(kb + ((16*g + 64) ^ sw));
            f4v z = (f4v){0.f, 0.f, 0.f, 0.f};
            z = __builtin_amdgcn_mfma_f32_16x16x32_bf16(qf0, kf0, z, 0, 0, 0);
            z = __builtin_amdgcn_mfma_f32_16x16x32_bf16(qf1, kf1, z, 0, 0, 0);
            #pragma unroll
            for (int i = 0; i < 4; i++) z[i] += madd[j];
            sj[j] = z;
        }
        __builtin_amdgcn_s_setprio(0);

        // ---- p = exp2(s), deferred per-lane l partials ----
        #pragma unroll
        for (int j = 0; j < 4; j++)
            #pragma unroll
            for (int i = 0; i < 4; i++)
                sj[j][i] = EXP2(sj[j][i]);
        #pragma unroll
        for (int i = 0; i < 4; i++)
            lsum[i] += (sj[0][i] + sj[1][i]) + (sj[2][i] + sj[3][i]);

        // ---- P -> bf16 (cvt_pk) -> per-wave LDS ----
        #pragma unroll
        for (int i = 0; i < 4; i++) {
            const int prow = 4*g + i;
            char* base = pb + prow * 128;
            const int sw = (prow & 7) << 4;
            unsigned p01 = cvt_pk_bf16(sj[0][i], sj[1][i]);
            unsigned p23 = cvt_pk_bf16(sj[2][i], sj[3][i]);
            *(short*)(base + (((16*0 + r) * 2) ^ sw)) = (short)(p01 & 0xffff);
            *(short*)(base + (((16*1 + r) * 2) ^ sw)) = (short)(p01 >> 16);
            *(short*)(base + (((16*2 + r) * 2) ^ sw)) = (short)(p23 & 0xffff);
            *(short*)(base + (((16*3 + r) * 2) ^ sw)) = (short)(p23 >> 16);
        }

        // ---- ctx += P @ V ----
        __builtin_amdgcn_s_setprio(1);
        #pragma unroll
        for (int c = 0; c < 2; c++) {
            s8v pf = *(const s8v*)(pb + r*128 + ((16*g + 64*c) ^ ((r & 7) << 4)));
            #pragma unroll
            for (int t4 = 0; t4 < 4; t4++) {
                const int vrow = 16*t4 + r;
                s8v vf = *(const s8v*)(Vc + vrow*128 + ((16*g + 64*c) ^ ((vrow & 7) << 4)));
                acc[t4] = __builtin_amdgcn_mfma_f32_16x16x32_bf16(pf, vf, acc[t4], 0, 0, 0);
            }
        }
        __builtin_amdgcn_s_setprio(0);

        __syncthreads();                     // all waves done reading pair pt
        if (pt + 1 < NPAIR) STOREP();        // write pair pt+1
        if (pt + 2 < NPAIR) LOADP(pt + 2);   // prefetch pair pt+2
        __syncthreads();                     // pair pt+1 ready
    }

    // ---- merge partials (fixed-max => plain adds) ----
    if (grp == 1) {
        float* mb = (float*)(lds + wq*5120 + lane*80);
        *(f4v*)(mb)      = acc[0];
        *(f4v*)(mb + 4)  = acc[1];
        *(f4v*)(mb + 8)  = acc[2];
        *(f4v*)(mb + 12) = acc[3];
        *(f4v*)(mb + 16) = lsum;
    }
    __syncthreads();
    if (grp == 0) {
        const float* mb = (const float*)(lds + wq*5120 + lane*80);
        acc[0] += *(const f4v*)(mb);
        acc[1] += *(const f4v*)(mb + 4);
        acc[2] += *(const f4v*)(mb + 8);
        acc[3] += *(const f4v*)(mb + 12);
        lsum   += *(const f4v*)(mb + 16);

        #pragma unroll
        for (int m = 1; m <= 8; m <<= 1) {
            lsum[0] += __shfl_xor(lsum[0], m);
            lsum[1] += __shfl_xor(lsum[1], m);
            lsum[2] += __shfl_xor(lsum[2], m);
            lsum[3] += __shfl_xor(lsum[3], m);
        }

        #pragma unroll
        for (int i = 0; i < 4; i++) {
            const float invl = 1.0f / lsum[i];
            const size_t rowbase = ((size_t)(b*SEQ) + q0 + wq*16 + 4*g + i) * HH + h*HDIM;
            #pragma unroll
            for (int t4 = 0; t4 < 4; t4++)
                CTX[rowbase + 16*t4 + r] = f2bf(acc[t4][i] * invl);
        }
    }
    #undef LOADP
    #undef STOREP
}

// ---------------------------------------------------------------------------
// In-place LayerNorm over rows of 768.
// ---------------------------------------------------------------------------
__global__ __launch_bounds__(256)
void ln_kernel(float* __restrict__ y, const float* __restrict__ gamma,
               const float* __restrict__ beta)
{
    const int row = blockIdx.x;
    float* p = y + (size_t)row * HH;
    const int tid = threadIdx.x;

    float v[3];
    float s = 0.f, ss = 0.f;
    #pragma unroll
    for (int i = 0; i < 3; i++) {
        float x = p[tid + i*256];
        v[i] = x;
        s += x;
        ss += x * x;
    }
    #pragma unroll
    for (int off = 32; off > 0; off >>= 1) {
        s  += __shfl_down(s,  off);
        ss += __shfl_down(ss, off);
    }
    __shared__ float sbuf[4], ssbuf[4];
    __shared__ float mu_s, rstd_s;
    const int wave = tid >> 6;
    if ((tid & 63) == 0) { sbuf[wave] = s; ssbuf[wave] = ss; }
    __syncthreads();
    if (tid == 0) {
        float S  = sbuf[0] + sbuf[1] + sbuf[2] + sbuf[3];
        float SS = ssbuf[0] + ssbuf[1] + ssbuf[2] + ssbuf[3];
        float mu = S * (1.0f / HH);
        float var = SS * (1.0f / HH) - mu * mu;
        mu_s = mu;
        rstd_s = rsqrtf(var + 1e-5f);
    }
    __syncthreads();
    const float mu = mu_s, rstd = rstd_s;
    #pragma unroll
    for (int i = 0; i < 3; i++) {
        const int c = tid + i*256;
        p[c] = (v[i] - mu) * rstd * gamma[c] + beta[c];
    }
}

// ---------------------------------------------------------------------------
extern "C" void kernel_launch(void* const* d_in, const int* in_sizes, int n_in,
                              void* d_out, int out_size, void* d_ws, size_t ws_size,
                              hipStream_t stream)
{
    const float* x     = (const float*)d_in[0];
    const float* mask  = (const float*)d_in[1];
    const float* Wq    = (const float*)d_in[2];
    const float* bq    = (const float*)d_in[3];
    const float* Wk    = (const float*)d_in[4];
    const float* bk    = (const float*)d_in[5];
    const float* Wv    = (const float*)d_in[6];
    const float* bv    = (const float*)d_in[7];
    const float* Wo    = (const float*)d_in[8];
    const float* bo    = (const float*)d_in[9];
    const float* gamma = (const float*)d_in[10];
    const float* beta  = (const float*)d_in[11];

    const size_t PER = (size_t)NB * NHEADS * SEQ * HDIM;
    const size_t WSZ = (size_t)HH * HH;
    short* wsS  = (short*)d_ws;
    short* Xb   = wsS;
    short* VTb  = wsS;
    short* Wqb  = wsS + PER;
    short* Wkb  = Wqb + WSZ;
    short* Wvb  = Wkb + WSZ;
    short* Wob  = Wvb + WSZ;
    short* Qb   = Wob + WSZ;
    short* Kb   = Qb + PER;
    short* Vb   = Kb + PER;
    short* CTXb = Vb;
    float* out  = (float*)d_out;

    cvt_kernel<<<2688, 256, 0, stream>>>(x, Xb, Wq, Wqb, Wk, Wkb, Wv, Wvb, Wo, Wob);

    gemm_mfma<0><<<dim3(18, 32), 256, 0, stream>>>(
        Xb, Wqb, Wkb, Wvb, bq, bk, bv, Qb, Kb, Vb, nullptr, nullptr);

    vtrans_kernel<<<dim3(SEQ/64, NHEADS, NB), 256, 0, stream>>>(Vb, VTb);

    attn_mfma<<<dim3(SEQ/64, NHEADS, NB), 512, 0, stream>>>(Qb, Kb, VTb, mask, CTXb);

    gemm_mfma<1><<<dim3(6, 32), 256, 0, stream>>>(
        CTXb, Wob, nullptr, nullptr, bo, nullptr, nullptr,
        nullptr, nullptr, nullptr, x, out);

    ln_kernel<<<NB*SEQ, 256, 0, stream>>>(out, gamma, beta);
}

// Round 6
// 134.233 us; speedup vs baseline: 1.3740x; 1.3740x over previous
//
#include <hip/hip_runtime.h>
#include <math.h>

#define HH 768
#define NHEADS 12
#define HDIM 64
#define SEQ 2048
#define NB 2
#define L2E 1.44269504088896f

typedef __attribute__((ext_vector_type(8))) short s8v;
typedef __attribute__((ext_vector_type(4))) short s4v;
typedef __attribute__((ext_vector_type(4))) float f4v;

static __device__ inline short f2bf(float f) {
    union { float f; unsigned u; } v; v.f = f;
    unsigned r = v.u + 0x7fff + ((v.u >> 16) & 1);   // RNE
    return (short)(r >> 16);
}

#if __has_builtin(__builtin_amdgcn_exp2f)
#define EXP2(x) __builtin_amdgcn_exp2f(x)
#else
#define EXP2(x) __expf((x) * 0.6931471805599453f)
#endif

__device__ __forceinline__ unsigned cvt_pk_bf16(float a, float b) {
    unsigned r;
    asm("v_cvt_pk_bf16_f32 %0, %1, %2" : "=v"(r) : "v"(a), "v"(b));
    return r;
}

__device__ __forceinline__ void gld16(const void* g, void* l) {
    __builtin_amdgcn_global_load_lds(
        (const __attribute__((address_space(1))) void*)g,
        (__attribute__((address_space(3))) void*)l, 16, 0, 0);
}

// ---------------------------------------------------------------------------
// fp32 -> bf16 conversion: X (4096x768) and the 4 weight matrices (768x768).
// ---------------------------------------------------------------------------
#define XV8   393216
#define WV8   73728
__global__ __launch_bounds__(256)
void cvt_kernel(const float* __restrict__ X, short* __restrict__ Xb,
                const float* __restrict__ W0, short* __restrict__ W0b,
                const float* __restrict__ W1, short* __restrict__ W1b,
                const float* __restrict__ W2, short* __restrict__ W2b,
                const float* __restrict__ W3, short* __restrict__ W3b)
{
    int gid = blockIdx.x * 256 + threadIdx.x;
    const float* src; short* dst; size_t off;
    if      (gid < XV8)            { src = X;  dst = Xb;  off = gid; }
    else if (gid < XV8 + WV8)      { src = W0; dst = W0b; off = gid - XV8; }
    else if (gid < XV8 + 2*WV8)    { src = W1; dst = W1b; off = gid - XV8 - WV8; }
    else if (gid < XV8 + 3*WV8)    { src = W2; dst = W2b; off = gid - XV8 - 2*WV8; }
    else if (gid < XV8 + 4*WV8)    { src = W3; dst = W3b; off = gid - XV8 - 3*WV8; }
    else return;
    off *= 8;
    float4 a = *(const float4*)(src + off);
    float4 b = *(const float4*)(src + off + 4);
    s8v o;
    o[0] = f2bf(a.x); o[1] = f2bf(a.y); o[2] = f2bf(a.z); o[3] = f2bf(a.w);
    o[4] = f2bf(b.x); o[5] = f2bf(b.y); o[6] = f2bf(b.z); o[7] = f2bf(b.w);
    *(s8v*)(dst + off) = o;
}

// ---------------------------------------------------------------------------
// MFMA GEMM, 128x128 tile, BK=32, 4 waves (2x2, 64x64 each).
// EPI 0: fused QKV -> bf16 [B,NH,S,HD], Q scaled by 0.125*log2(e).
// EPI 1: out-proj -> fp32 [4096,768] + bias + residual.
// ---------------------------------------------------------------------------
template<int EPI>
__global__ __launch_bounds__(256)
void gemm_mfma(const short* __restrict__ A,
               const short* __restrict__ Wq, const short* __restrict__ Wk,
               const short* __restrict__ Wv,
               const float* __restrict__ bq, const float* __restrict__ bk,
               const float* __restrict__ bv,
               short* __restrict__ Qo, short* __restrict__ Ko, short* __restrict__ Vo,
               const float* __restrict__ Xres, float* __restrict__ Fo)
{
    __shared__ __align__(16) short As[128*32];
    __shared__ __align__(16) short Bs[128*32];

    const int tid  = threadIdx.x;
    const int w    = tid >> 6;
    const int lane = tid & 63;
    const int g    = lane >> 4;
    const int r    = lane & 15;
    const int wr   = w >> 1;
    const int wc   = w & 1;
    const int m0   = blockIdx.y * 128;

    int n0;
    const short* Wb; const float* bias; short* outp; float scale;
    if (EPI == 0) {
        const int seg = blockIdx.x / 6;
        n0 = (blockIdx.x % 6) * 128;
        Wb   = seg == 0 ? Wq : seg == 1 ? Wk : Wv;
        bias = seg == 0 ? bq : seg == 1 ? bk : bv;
        outp = seg == 0 ? Qo : seg == 1 ? Ko : Vo;
        scale = seg == 0 ? (0.125f * L2E) : 1.0f;
    } else {
        n0 = blockIdx.x * 128;
        Wb = Wq; bias = bq; outp = nullptr; scale = 1.0f;
    }

    const int lrow = lane >> 2;
    const int lcol = (lane & 3) * 8;
    const short* Ag0 = A  + (size_t)(m0 + w*32 + lrow) * HH + lcol;
    const short* Bg0 = Wb + (size_t)(n0 + w*32 + lrow) * HH + lcol;
    short* Al0 = As + (w*32)      * 32;
    short* Al1 = As + (w*32 + 16) * 32;
    short* Bl0 = Bs + (w*32)      * 32;
    short* Bl1 = Bs + (w*32 + 16) * 32;

    f4v acc[4][4];
    #pragma unroll
    for (int i = 0; i < 4; i++)
        #pragma unroll
        for (int j = 0; j < 4; j++) acc[i][j] = (f4v){0.f,0.f,0.f,0.f};

    for (int kt = 0; kt < HH/32; ++kt) {
        const int k0 = kt * 32;
        gld16(Ag0 + k0,           Al0);
        gld16(Ag0 + k0 + 16*HH,   Al1);
        gld16(Bg0 + k0,           Bl0);
        gld16(Bg0 + k0 + 16*HH,   Bl1);
        __syncthreads();

        s8v af[4], bf[4];
        #pragma unroll
        for (int mi = 0; mi < 4; mi++)
            af[mi] = *(const s8v*)(As + (wr*64 + mi*16 + r)*32 + g*8);
        #pragma unroll
        for (int ni = 0; ni < 4; ni++)
            bf[ni] = *(const s8v*)(Bs + (wc*64 + ni*16 + r)*32 + g*8);
        __builtin_amdgcn_s_setprio(1);
        #pragma unroll
        for (int mi = 0; mi < 4; mi++)
            #pragma unroll
            for (int ni = 0; ni < 4; ni++)
                acc[mi][ni] = __builtin_amdgcn_mfma_f32_16x16x32_bf16(af[mi], bf[ni], acc[mi][ni], 0, 0, 0);
        __builtin_amdgcn_s_setprio(0);
        __syncthreads();
    }

    if (EPI == 0) {
        #pragma unroll
        for (int mi = 0; mi < 4; mi++) {
            #pragma unroll
            for (int j = 0; j < 4; j++) {
                const int m = m0 + wr*64 + mi*16 + 4*g + j;
                const int bb = m >> 11;
                const int s  = m & 2047;
                #pragma unroll
                for (int ni = 0; ni < 4; ni++) {
                    const int n = n0 + wc*64 + ni*16 + r;
                    const int h = n >> 6;
                    const int d = n & 63;
                    outp[((size_t)((bb*NHEADS + h)*SEQ) + s)*HDIM + d] =
                        f2bf((acc[mi][ni][j] + bias[n]) * scale);
                }
            }
        }
    } else {
        #pragma unroll
        for (int mi = 0; mi < 4; mi++) {
            #pragma unroll
            for (int j = 0; j < 4; j++) {
                const int m = m0 + wr*64 + mi*16 + 4*g + j;
                #pragma unroll
                for (int ni = 0; ni < 4; ni++) {
                    const int n = n0 + wc*64 + ni*16 + r;
                    Fo[(size_t)m*HH + n] = acc[mi][ni][j] + bias[n] + Xres[(size_t)m*HH + n];
                }
            }
        }
    }
}

// ---------------------------------------------------------------------------
// V [B,NH,S,HD] -> VT [B,NH,HD,S], 64x64 LDS tiles.
// ---------------------------------------------------------------------------
__global__ __launch_bounds__(256)
void vtrans_kernel(const short* __restrict__ V, short* __restrict__ VT)
{
    const int st = blockIdx.x;
    const int h  = blockIdx.y;
    const int b  = blockIdx.z;
    __shared__ short T[64][72];
    const int t = threadIdx.x;
    const short* src = V + ((size_t)(b*NHEADS + h)*SEQ + st*64) * HDIM;

    {
        const int sl = t >> 2;
        const int dq = (t & 3) * 16;
        s8v a = *(const s8v*)(src + sl*HDIM + dq);
        s8v c = *(const s8v*)(src + sl*HDIM + dq + 8);
        #pragma unroll
        for (int i = 0; i < 8; i++) { T[dq+i][sl] = a[i]; T[dq+8+i][sl] = c[i]; }
    }
    __syncthreads();
    {
        const int d  = t >> 2;
        const int sq = (t & 3) * 16;
        s8v o0 = *(const s8v*)&T[d][sq];
        s8v o1 = *(const s8v*)&T[d][sq+8];
        short* dst = VT + ((size_t)(b*NHEADS + h)*HDIM + d)*SEQ + st*64 + sq;
        *(s8v*)(dst)     = o0;
        *(s8v*)(dst + 8) = o1;
    }
}

// ---------------------------------------------------------------------------
// Flash attention, bf16 MFMA, 8 waves / 512 threads, KV-parity split.
// Fixed-max exp2 softmax (exact: shift-invariance + bounded scores).
// K/V staged via global_load_lds with PRE-SWIZZLED global source columns
// (LDS dest linear; read-side XOR swizzle matches; G21 both-sides rule).
// Pair-double-buffered LDS: 2*(16K K + 16K V) + 16K P = 80 KB -> 2 blk/CU.
// Q pre-scaled by 0.125*log2e. K: [B,NH,S,HD]. VT: [B,NH,HD,S]. CTX: bf16.
// ---------------------------------------------------------------------------
#define NT (SEQ/64)
#define NPAIR (NT/2)
__global__ __launch_bounds__(512, 4)
void attn_mfma(const short* __restrict__ Q, const short* __restrict__ K,
               const short* __restrict__ VT, const float* __restrict__ mask,
               short* __restrict__ CTX)
{
    const int qt = blockIdx.x;
    const int h  = blockIdx.y;
    const int b  = blockIdx.z;
    const size_t hb = (size_t)(b * NHEADS + h);
    const short* Qg  = Q  + hb * SEQ * HDIM;
    const short* Kg  = K  + hb * SEQ * HDIM;
    const short* VTg = VT + hb * HDIM * SEQ;

    __shared__ __align__(16) char lds[81920];
    char* Kbase = lds;            // [db][par][64 rows][128B]  (2*16 KB)
    char* Vbase = lds + 32768;    // [db][par][64 rows][128B]  (2*16 KB)
    char* Pbase = lds + 65536;    // [8 waves][16 rows][128B]  (16 KB)

    const int tid  = threadIdx.x;
    const int w    = tid >> 6;
    const int grp  = w >> 2;      // tile parity group
    const int wq   = w & 3;       // q-subtile owner
    const int lane = tid & 63;
    const int g    = lane >> 4;
    const int r    = lane & 15;
    const int q0   = qt * 64;

    const short* qrow = Qg + (size_t)(q0 + wq*16 + r) * HDIM;
    const s8v qf0 = *(const s8v*)(qrow + 8*g);
    const s8v qf1 = *(const s8v*)(qrow + 8*g + 32);

    f4v acc[4];
    #pragma unroll
    for (int t = 0; t < 4; t++) acc[t] = (f4v){0.f, 0.f, 0.f, 0.f};
    f4v lsum = (f4v){0.f, 0.f, 0.f, 0.f};

    // per-lane pre-swizzled source column (elements):
    // LDS linear dest (row, 16B-col lane&7); read swizzle = ((row&7)<<4) bytes.
    const int lrow8 = lane >> 3;                               // row within 8-row chunk
    const int lcolE = ((lane & 7) * 8) ^ ((lrow8 & 7) << 3);   // swizzled col, elems

    // wave 0-3: stage K pair rows w*32 .. w*32+32 (4 chunks of 8 rows)
    // wave 4-7: stage V^T: wv=w-4, d rows wv*16..+16, both parities (4 chunks)
    #define STAGE(PAIR, DB) do {                                              \
        const int pk0 = (PAIR) * 128;                                         \
        if (w < 4) {                                                          \
            char* dst = Kbase + (DB)*16384 + (w*32)*128;                      \
            const short* src = Kg + (size_t)(pk0 + w*32 + lrow8)*HDIM + lcolE;\
            gld16(src,           dst);                                        \
            gld16(src +  8*HDIM, dst + 1024);                                 \
            gld16(src + 16*HDIM, dst + 2048);                                 \
            gld16(src + 24*HDIM, dst + 3072);                                 \
        } else {                                                              \
            const int wv = w - 4;                                             \
            char* dst = Vbase + (DB)*16384 + (wv*16)*128;                     \
            const short* src = VTg + (size_t)(wv*16 + lrow8)*SEQ + pk0 + lcolE;\
            gld16(src,            dst);                                       \
            gld16(src + 8*SEQ,    dst + 1024);                                \
            gld16(src + 64,       dst + 8192);                                \
            gld16(src + 8*SEQ+64, dst + 8192 + 1024);                         \
        }                                                                     \
    } while (0)

    STAGE(0, 0);
    __syncthreads();

    char* pb = Pbase + w*2048;

    for (int pt = 0; pt < NPAIR; ++pt) {
        const int db = pt & 1;
        if (pt + 1 < NPAIR) STAGE(pt + 1, db ^ 1);   // async, drained at barrier

        const char* Kc = Kbase + db*16384 + grp*8192;
        const char* Vc = Vbase + db*16384 + grp*8192;
        const int k0 = (2*pt + grp) * 64;

        float madd[4];
        #pragma unroll
        for (int j = 0; j < 4; j++)
            madd[j] = (mask[b*SEQ + k0 + 16*j + r] - 1.0f) * (10000.0f * L2E);

        // ---- QK^T (log2-space scores) ----
        f4v sj[4];
        __builtin_amdgcn_s_setprio(1);
        #pragma unroll
        for (int j = 0; j < 4; j++) {
            const int krow = 16*j + r;
            const char* kb = Kc + krow * 128;
            const int sw = (krow & 7) << 4;
            s8v kf0 = *(const s8v*)(kb + ((16*g)      ^ sw));
            s8v kf1 = *(const s8v*)(kb + ((16*g + 64) ^ sw));
            f4v z = (f4v){0.f, 0.f, 0.f, 0.f};
            z = __builtin_amdgcn_mfma_f32_16x16x32_bf16(qf0, kf0, z, 0, 0, 0);
            z = __builtin_amdgcn_mfma_f32_16x16x32_bf16(qf1, kf1, z, 0, 0, 0);
            #pragma unroll
            for (int i = 0; i < 4; i++) z[i] += madd[j];
            sj[j] = z;
        }
        __builtin_amdgcn_s_setprio(0);

        // ---- p = exp2(s), per-lane l partials (no shuffles in loop) ----
        #pragma unroll
        for (int j = 0; j < 4; j++)
            #pragma unroll
            for (int i = 0; i < 4; i++)
                sj[j][i] = EXP2(sj[j][i]);
        #pragma unroll
        for (int i = 0; i < 4; i++)
            lsum[i] += (sj[0][i] + sj[1][i]) + (sj[2][i] + sj[3][i]);

        // ---- P -> bf16 (cvt_pk) -> per-wave LDS ----
        #pragma unroll
        for (int i = 0; i < 4; i++) {
            const int prow = 4*g + i;
            char* base = pb + prow * 128;
            const int sw = (prow & 7) << 4;
            unsigned p01 = cvt_pk_bf16(sj[0][i], sj[1][i]);
            unsigned p23 = cvt_pk_bf16(sj[2][i], sj[3][i]);
            *(short*)(base + (((16*0 + r) * 2) ^ sw)) = (short)(p01 & 0xffff);
            *(short*)(base + (((16*1 + r) * 2) ^ sw)) = (short)(p01 >> 16);
            *(short*)(base + (((16*2 + r) * 2) ^ sw)) = (short)(p23 & 0xffff);
            *(short*)(base + (((16*3 + r) * 2) ^ sw)) = (short)(p23 >> 16);
        }

        // ---- ctx += P @ V ----
        __builtin_amdgcn_s_setprio(1);
        #pragma unroll
        for (int c = 0; c < 2; c++) {
            s8v pf = *(const s8v*)(pb + r*128 + ((16*g + 64*c) ^ ((r & 7) << 4)));
            #pragma unroll
            for (int t4 = 0; t4 < 4; t4++) {
                const int vrow = 16*t4 + r;
                s8v vf = *(const s8v*)(Vc + vrow*128 + ((16*g + 64*c) ^ ((vrow & 7) << 4)));
                acc[t4] = __builtin_amdgcn_mfma_f32_16x16x32_bf16(pf, vf, acc[t4], 0, 0, 0);
            }
        }
        __builtin_amdgcn_s_setprio(0);

        __syncthreads();   // drains prefetch vmcnt; next pair ready, bufs free
    }

    // ---- merge parity partials (fixed-max => plain adds) ----
    if (grp == 1) {
        float* mb = (float*)(lds + wq*5120 + lane*80);
        *(f4v*)(mb)      = acc[0];
        *(f4v*)(mb + 4)  = acc[1];
        *(f4v*)(mb + 8)  = acc[2];
        *(f4v*)(mb + 12) = acc[3];
        *(f4v*)(mb + 16) = lsum;
    }
    __syncthreads();
    if (grp == 0) {
        const float* mb = (const float*)(lds + wq*5120 + lane*80);
        acc[0] += *(const f4v*)(mb);
        acc[1] += *(const f4v*)(mb + 4);
        acc[2] += *(const f4v*)(mb + 8);
        acc[3] += *(const f4v*)(mb + 12);
        lsum   += *(const f4v*)(mb + 16);

        #pragma unroll
        for (int m = 1; m <= 8; m <<= 1) {
            lsum[0] += __shfl_xor(lsum[0], m);
            lsum[1] += __shfl_xor(lsum[1], m);
            lsum[2] += __shfl_xor(lsum[2], m);
            lsum[3] += __shfl_xor(lsum[3], m);
        }

        #pragma unroll
        for (int i = 0; i < 4; i++) {
            const float invl = 1.0f / lsum[i];
            const size_t rowbase = ((size_t)(b*SEQ) + q0 + wq*16 + 4*g + i) * HH + h*HDIM;
            #pragma unroll
            for (int t4 = 0; t4 < 4; t4++)
                CTX[rowbase + 16*t4 + r] = f2bf(acc[t4][i] * invl);
        }
    }
    #undef STAGE
}

// ---------------------------------------------------------------------------
// In-place LayerNorm over rows of 768.
// ---------------------------------------------------------------------------
__global__ __launch_bounds__(256)
void ln_kernel(float* __restrict__ y, const float* __restrict__ gamma,
               const float* __restrict__ beta)
{
    const int row = blockIdx.x;
    float* p = y + (size_t)row * HH;
    const int tid = threadIdx.x;

    float v[3];
    float s = 0.f, ss = 0.f;
    #pragma unroll
    for (int i = 0; i < 3; i++) {
        float x = p[tid + i*256];
        v[i] = x;
        s += x;
        ss += x * x;
    }
    #pragma unroll
    for (int off = 32; off > 0; off >>= 1) {
        s  += __shfl_down(s,  off);
        ss += __shfl_down(ss, off);
    }
    __shared__ float sbuf[4], ssbuf[4];
    __shared__ float mu_s, rstd_s;
    const int wave = tid >> 6;
    if ((tid & 63) == 0) { sbuf[wave] = s; ssbuf[wave] = ss; }
    __syncthreads();
    if (tid == 0) {
        float S  = sbuf[0] + sbuf[1] + sbuf[2] + sbuf[3];
        float SS = ssbuf[0] + ssbuf[1] + ssbuf[2] + ssbuf[3];
        float mu = S * (1.0f / HH);
        float var = SS * (1.0f / HH) - mu * mu;
        mu_s = mu;
        rstd_s = rsqrtf(var + 1e-5f);
    }
    __syncthreads();
    const float mu = mu_s, rstd = rstd_s;
    #pragma unroll
    for (int i = 0; i < 3; i++) {
        const int c = tid + i*256;
        p[c] = (v[i] - mu) * rstd * gamma[c] + beta[c];
    }
}

// ---------------------------------------------------------------------------
extern "C" void kernel_launch(void* const* d_in, const int* in_sizes, int n_in,
                              void* d_out, int out_size, void* d_ws, size_t ws_size,
                              hipStream_t stream)
{
    const float* x     = (const float*)d_in[0];
    const float* mask  = (const float*)d_in[1];
    const float* Wq    = (const float*)d_in[2];
    const float* bq    = (const float*)d_in[3];
    const float* Wk    = (const float*)d_in[4];
    const float* bk    = (const float*)d_in[5];
    const float* Wv    = (const float*)d_in[6];
    const float* bv    = (const float*)d_in[7];
    const float* Wo    = (const float*)d_in[8];
    const float* bo    = (const float*)d_in[9];
    const float* gamma = (const float*)d_in[10];
    const float* beta  = (const float*)d_in[11];

    const size_t PER = (size_t)NB * NHEADS * SEQ * HDIM;
    const size_t WSZ = (size_t)HH * HH;
    short* wsS  = (short*)d_ws;
    short* Xb   = wsS;
    short* VTb  = wsS;
    short* Wqb  = wsS + PER;
    short* Wkb  = Wqb + WSZ;
    short* Wvb  = Wkb + WSZ;
    short* Wob  = Wvb + WSZ;
    short* Qb   = Wob + WSZ;
    short* Kb   = Qb + PER;
    short* Vb   = Kb + PER;
    short* CTXb = Vb;
    float* out  = (float*)d_out;

    cvt_kernel<<<2688, 256, 0, stream>>>(x, Xb, Wq, Wqb, Wk, Wkb, Wv, Wvb, Wo, Wob);

    gemm_mfma<0><<<dim3(18, 32), 256, 0, stream>>>(
        Xb, Wqb, Wkb, Wvb, bq, bk, bv, Qb, Kb, Vb, nullptr, nullptr);

    vtrans_kernel<<<dim3(SEQ/64, NHEADS, NB), 256, 0, stream>>>(Vb, VTb);

    attn_mfma<<<dim3(SEQ/64, NHEADS, NB), 512, 0, stream>>>(Qb, Kb, VTb, mask, CTXb);

    gemm_mfma<1><<<dim3(6, 32), 256, 0, stream>>>(
        CTXb, Wob, nullptr, nullptr, bo, nullptr, nullptr,
        nullptr, nullptr, nullptr, x, out);

    ln_kernel<<<NB*SEQ, 256, 0, stream>>>(out, gamma, beta);
}

// Round 7
// 130.614 us; speedup vs baseline: 1.4121x; 1.0277x over previous
//
#include <hip/hip_runtime.h>
#include <math.h>

#define HH 768
#define NHEADS 12
#define HDIM 64
#define SEQ 2048
#define NB 2
#define L2E 1.44269504088896f

typedef __attribute__((ext_vector_type(8))) short s8v;
typedef __attribute__((ext_vector_type(4))) short s4v;
typedef __attribute__((ext_vector_type(4))) float f4v;

static __device__ inline short f2bf(float f) {
    union { float f; unsigned u; } v; v.f = f;
    unsigned r = v.u + 0x7fff + ((v.u >> 16) & 1);   // RNE
    return (short)(r >> 16);
}

#if __has_builtin(__builtin_amdgcn_exp2f)
#define EXP2(x) __builtin_amdgcn_exp2f(x)
#else
#define EXP2(x) __expf((x) * 0.6931471805599453f)
#endif

__device__ __forceinline__ unsigned cvt_pk_bf16(float a, float b) {
    unsigned r;
    asm("v_cvt_pk_bf16_f32 %0, %1, %2" : "=v"(r) : "v"(a), "v"(b));
    return r;
}

__device__ __forceinline__ void gld16(const void* g, void* l) {
    __builtin_amdgcn_global_load_lds(
        (const __attribute__((address_space(1))) void*)g,
        (__attribute__((address_space(3))) void*)l, 16, 0, 0);
}

// ---------------------------------------------------------------------------
// fp32 -> bf16 conversion: X (4096x768) and the 4 weight matrices (768x768).
// ---------------------------------------------------------------------------
#define XV8   393216
#define WV8   73728
__global__ __launch_bounds__(256)
void cvt_kernel(const float* __restrict__ X, short* __restrict__ Xb,
                const float* __restrict__ W0, short* __restrict__ W0b,
                const float* __restrict__ W1, short* __restrict__ W1b,
                const float* __restrict__ W2, short* __restrict__ W2b,
                const float* __restrict__ W3, short* __restrict__ W3b)
{
    int gid = blockIdx.x * 256 + threadIdx.x;
    const float* src; short* dst; size_t off;
    if      (gid < XV8)            { src = X;  dst = Xb;  off = gid; }
    else if (gid < XV8 + WV8)      { src = W0; dst = W0b; off = gid - XV8; }
    else if (gid < XV8 + 2*WV8)    { src = W1; dst = W1b; off = gid - XV8 - WV8; }
    else if (gid < XV8 + 3*WV8)    { src = W2; dst = W2b; off = gid - XV8 - 2*WV8; }
    else if (gid < XV8 + 4*WV8)    { src = W3; dst = W3b; off = gid - XV8 - 3*WV8; }
    else return;
    off *= 8;
    float4 a = *(const float4*)(src + off);
    float4 b = *(const float4*)(src + off + 4);
    s8v o;
    o[0] = f2bf(a.x); o[1] = f2bf(a.y); o[2] = f2bf(a.z); o[3] = f2bf(a.w);
    o[4] = f2bf(b.x); o[5] = f2bf(b.y); o[6] = f2bf(b.z); o[7] = f2bf(b.w);
    *(s8v*)(dst + off) = o;
}

// ---------------------------------------------------------------------------
// MFMA GEMM, 128x128 tile, BK=32, 4 waves (2x2, 64x64 each).
// EPI 0: fused QKV -> bf16 [B,NH,S,HD], Q scaled by 0.125*log2(e).
// EPI 1: out-proj -> fp32 [4096,768] + bias + residual.
// ---------------------------------------------------------------------------
template<int EPI>
__global__ __launch_bounds__(256)
void gemm_mfma(const short* __restrict__ A,
               const short* __restrict__ Wq, const short* __restrict__ Wk,
               const short* __restrict__ Wv,
               const float* __restrict__ bq, const float* __restrict__ bk,
               const float* __restrict__ bv,
               short* __restrict__ Qo, short* __restrict__ Ko, short* __restrict__ Vo,
               const float* __restrict__ Xres, float* __restrict__ Fo)
{
    __shared__ __align__(16) short As[128*32];
    __shared__ __align__(16) short Bs[128*32];

    const int tid  = threadIdx.x;
    const int w    = tid >> 6;
    const int lane = tid & 63;
    const int g    = lane >> 4;
    const int r    = lane & 15;
    const int wr   = w >> 1;
    const int wc   = w & 1;
    const int m0   = blockIdx.y * 128;

    int n0;
    const short* Wb; const float* bias; short* outp; float scale;
    if (EPI == 0) {
        const int seg = blockIdx.x / 6;
        n0 = (blockIdx.x % 6) * 128;
        Wb   = seg == 0 ? Wq : seg == 1 ? Wk : Wv;
        bias = seg == 0 ? bq : seg == 1 ? bk : bv;
        outp = seg == 0 ? Qo : seg == 1 ? Ko : Vo;
        scale = seg == 0 ? (0.125f * L2E) : 1.0f;
    } else {
        n0 = blockIdx.x * 128;
        Wb = Wq; bias = bq; outp = nullptr; scale = 1.0f;
    }

    const int lrow = lane >> 2;
    const int lcol = (lane & 3) * 8;
    const short* Ag0 = A  + (size_t)(m0 + w*32 + lrow) * HH + lcol;
    const short* Bg0 = Wb + (size_t)(n0 + w*32 + lrow) * HH + lcol;
    short* Al0 = As + (w*32)      * 32;
    short* Al1 = As + (w*32 + 16) * 32;
    short* Bl0 = Bs + (w*32)      * 32;
    short* Bl1 = Bs + (w*32 + 16) * 32;

    f4v acc[4][4];
    #pragma unroll
    for (int i = 0; i < 4; i++)
        #pragma unroll
        for (int j = 0; j < 4; j++) acc[i][j] = (f4v){0.f,0.f,0.f,0.f};

    for (int kt = 0; kt < HH/32; ++kt) {
        const int k0 = kt * 32;
        gld16(Ag0 + k0,           Al0);
        gld16(Ag0 + k0 + 16*HH,   Al1);
        gld16(Bg0 + k0,           Bl0);
        gld16(Bg0 + k0 + 16*HH,   Bl1);
        __syncthreads();

        s8v af[4], bf[4];
        #pragma unroll
        for (int mi = 0; mi < 4; mi++)
            af[mi] = *(const s8v*)(As + (wr*64 + mi*16 + r)*32 + g*8);
        #pragma unroll
        for (int ni = 0; ni < 4; ni++)
            bf[ni] = *(const s8v*)(Bs + (wc*64 + ni*16 + r)*32 + g*8);
        __builtin_amdgcn_s_setprio(1);
        #pragma unroll
        for (int mi = 0; mi < 4; mi++)
            #pragma unroll
            for (int ni = 0; ni < 4; ni++)
                acc[mi][ni] = __builtin_amdgcn_mfma_f32_16x16x32_bf16(af[mi], bf[ni], acc[mi][ni], 0, 0, 0);
        __builtin_amdgcn_s_setprio(0);
        __syncthreads();
    }

    if (EPI == 0) {
        #pragma unroll
        for (int mi = 0; mi < 4; mi++) {
            #pragma unroll
            for (int j = 0; j < 4; j++) {
                const int m = m0 + wr*64 + mi*16 + 4*g + j;
                const int bb = m >> 11;
                const int s  = m & 2047;
                #pragma unroll
                for (int ni = 0; ni < 4; ni++) {
                    const int n = n0 + wc*64 + ni*16 + r;
                    const int h = n >> 6;
                    const int d = n & 63;
                    outp[((size_t)((bb*NHEADS + h)*SEQ) + s)*HDIM + d] =
                        f2bf((acc[mi][ni][j] + bias[n]) * scale);
                }
            }
        }
    } else {
        #pragma unroll
        for (int mi = 0; mi < 4; mi++) {
            #pragma unroll
            for (int j = 0; j < 4; j++) {
                const int m = m0 + wr*64 + mi*16 + 4*g + j;
                #pragma unroll
                for (int ni = 0; ni < 4; ni++) {
                    const int n = n0 + wc*64 + ni*16 + r;
                    Fo[(size_t)m*HH + n] = acc[mi][ni][j] + bias[n] + Xres[(size_t)m*HH + n];
                }
            }
        }
    }
}

// ---------------------------------------------------------------------------
// V [B,NH,S,HD] -> VT [B,NH,HD,S], 64x64 LDS tiles.
// ---------------------------------------------------------------------------
__global__ __launch_bounds__(256)
void vtrans_kernel(const short* __restrict__ V, short* __restrict__ VT)
{
    const int st = blockIdx.x;
    const int h  = blockIdx.y;
    const int b  = blockIdx.z;
    __shared__ short T[64][72];
    const int t = threadIdx.x;
    const short* src = V + ((size_t)(b*NHEADS + h)*SEQ + st*64) * HDIM;

    {
        const int sl = t >> 2;
        const int dq = (t & 3) * 16;
        s8v a = *(const s8v*)(src + sl*HDIM + dq);
        s8v c = *(const s8v*)(src + sl*HDIM + dq + 8);
        #pragma unroll
        for (int i = 0; i < 8; i++) { T[dq+i][sl] = a[i]; T[dq+8+i][sl] = c[i]; }
    }
    __syncthreads();
    {
        const int d  = t >> 2;
        const int sq = (t & 3) * 16;
        s8v o0 = *(const s8v*)&T[d][sq];
        s8v o1 = *(const s8v*)&T[d][sq+8];
        short* dst = VT + ((size_t)(b*NHEADS + h)*HDIM + d)*SEQ + st*64 + sq;
        *(s8v*)(dst)     = o0;
        *(s8v*)(dst + 8) = o1;
    }
}

// ---------------------------------------------------------------------------
// Flash attention, bf16 MFMA, 8 waves / 512 threads, KV-parity split.
// Pair = 64 contiguous k-rows; parity group grp handles 32-row half.
// Fixed-max exp2 softmax, per-lane deferred l, LDS merge at end.
// LDS 40 KB (K 2x8K dbuf, V 2x8K dbuf, P 8K) -> 3 blocks/CU resident,
// grid 768 = one full-residency round. Bijective XCD swizzle (768 = 8*96).
// All LDS tiles XOR-slot-swizzled; gld16 keeps LDS dest linear and applies
// the inverse swizzle on the global source column (G21 both-sides rule).
// ---------------------------------------------------------------------------
#define NPAIR (SEQ/64)
__global__ __launch_bounds__(512, 4)
void attn_mfma(const short* __restrict__ Q, const short* __restrict__ K,
               const short* __restrict__ VT, const float* __restrict__ mask,
               short* __restrict__ CTX)
{
    // XCD swizzle: 768 blocks = 8 XCDs x 96; contiguous 96-chunk per XCD
    const int wgid = (blockIdx.x & 7) * 96 + (blockIdx.x >> 3);
    const int qt = wgid & 31;
    const int bh = wgid >> 5;          // 0..23
    const int h  = bh % NHEADS;
    const int b  = bh / NHEADS;

    const size_t hb = (size_t)(b * NHEADS + h);
    const short* Qg  = Q  + hb * SEQ * HDIM;
    const short* Kg  = K  + hb * SEQ * HDIM;
    const short* VTg = VT + hb * HDIM * SEQ;

    __shared__ __align__(16) char lds[40960];
    char* Kbase = lds;            // [2 db][64 rows][128B]
    char* Vbase = lds + 16384;    // [2 db][2 par][64 d-rows][64B]
    char* Pbase = lds + 32768;    // [8 waves][16 q-rows][64B]

    const int tid  = threadIdx.x;
    const int w    = tid >> 6;
    const int grp  = w >> 2;      // parity: which 32-row half of the pair
    const int wq   = w & 3;       // q-subtile owner
    const int lane = tid & 63;
    const int g    = lane >> 4;
    const int r    = lane & 15;
    const int q0   = qt * 64;

    const short* qrow = Qg + (size_t)(q0 + wq*16 + r) * HDIM;
    const s8v qf0 = *(const s8v*)(qrow + 8*g);
    const s8v qf1 = *(const s8v*)(qrow + 8*g + 32);

    f4v acc[4];
    #pragma unroll
    for (int t = 0; t < 4; t++) acc[t] = (f4v){0.f, 0.f, 0.f, 0.f};
    f4v lsum = (f4v){0.f, 0.f, 0.f, 0.f};

    // K staging: wave w stages rows 8w..8w+7 (lane>>3 within), slot lane&7.
    const int srK  = lane >> 3;                       // row within wave chunk (row&7)
    const int scK  = ((lane & 7) * 8) ^ (srK << 3);   // pre-swizzled col, elems
    // V staging: par = w>>2, d = (w&3)*16 + (lane>>2), lin-slot = lane&3.
    const int dV   = (w & 3) * 16 + (lane >> 2);
    const int scV  = ((lane & 3) ^ (dV & 3)) * 8;     // pre-swizzled col, elems
    const int parV = w >> 2;

    #define STAGE(PT, DB) do {                                                 \
        const int pk0 = (PT) * 64;                                             \
        char* kd = Kbase + (DB)*8192 + w*1024;                                 \
        gld16(Kg + (size_t)(pk0 + 8*w + srK)*HDIM + scK, kd);                  \
        char* vd = Vbase + (DB)*8192 + w*1024;                                 \
        gld16(VTg + (size_t)dV*SEQ + pk0 + parV*32 + scV, vd);                 \
    } while (0)

    STAGE(0, 0);
    __syncthreads();

    char* pb = Pbase + w*1024;
    const int keyr = (r & 3) ^ ((r >> 2) & 3);   // P read key for row q=r

    for (int pt = 0; pt < NPAIR; ++pt) {
        const int db = pt & 1;
        if (pt + 1 < NPAIR) STAGE(pt + 1, db ^ 1);   // async, drained at barrier

        const char* Kc = Kbase + db*8192 + grp*4096; // 32 rows x 128B
        const char* Vc = Vbase + db*8192 + grp*4096; // 64 d-rows x 64B
        const int k0 = pt*64 + grp*32;

        float madd[2];
        madd[0] = (mask[b*SEQ + k0 + r]      - 1.0f) * (10000.0f * L2E);
        madd[1] = (mask[b*SEQ + k0 + 16 + r] - 1.0f) * (10000.0f * L2E);

        // ---- QK^T (log2-space scores), k-extent 32 ----
        f4v sj[2];
        __builtin_amdgcn_s_setprio(1);
        #pragma unroll
        for (int j = 0; j < 2; j++) {
            const int krow = 16*j + r;
            const char* kb = Kc + krow * 128;
            const int sw = (r & 7) << 4;             // krow&7 == r&7
            s8v kf0 = *(const s8v*)(kb + ((16*g)      ^ sw));
            s8v kf1 = *(const s8v*)(kb + ((16*g + 64) ^ sw));
            f4v z = (f4v){0.f, 0.f, 0.f, 0.f};
            z = __builtin_amdgcn_mfma_f32_16x16x32_bf16(qf0, kf0, z, 0, 0, 0);
            z = __builtin_amdgcn_mfma_f32_16x16x32_bf16(qf1, kf1, z, 0, 0, 0);
            #pragma unroll
            for (int i = 0; i < 4; i++) z[i] += madd[j];
            sj[j] = z;
        }
        __builtin_amdgcn_s_setprio(0);

        // ---- p = exp2(s), per-lane l partials ----
        #pragma unroll
        for (int j = 0; j < 2; j++)
            #pragma unroll
            for (int i = 0; i < 4; i++)
                sj[j][i] = EXP2(sj[j][i]);
        #pragma unroll
        for (int i = 0; i < 4; i++)
            lsum[i] += sj[0][i] + sj[1][i];

        // ---- P -> bf16 -> per-wave LDS (64B rows, slot ^ key(q)) ----
        #pragma unroll
        for (int i = 0; i < 4; i++) {
            const int keyq = i ^ g;                  // (q&3)^((q>>2)&3), q=4g+i
            char* base = pb + (4*g + i) * 64;
            unsigned u = cvt_pk_bf16(sj[0][i], sj[1][i]);
            *(short*)(base + ((((r>>3)     ^ keyq) << 4) | ((r & 7) * 2))) = (short)(u & 0xffff);
            *(short*)(base + (((2+(r>>3))  ^ keyq) << 4) + ((r & 7) * 2))  = (short)(u >> 16);
        }

        // ---- ctx += P @ V (k-extent 32) ----
        __builtin_amdgcn_s_setprio(1);
        {
            s8v pf = *(const s8v*)(pb + r*64 + ((g ^ keyr) << 4));
            #pragma unroll
            for (int t4 = 0; t4 < 4; t4++) {
                const int vrow = 16*t4 + r;
                s8v vf = *(const s8v*)(Vc + vrow*64 + ((g ^ (r & 3)) << 4));
                acc[t4] = __builtin_amdgcn_mfma_f32_16x16x32_bf16(pf, vf, acc[t4], 0, 0, 0);
            }
        }
        __builtin_amdgcn_s_setprio(0);

        __syncthreads();   // drains prefetch vmcnt; next pair ready, bufs free
    }

    // ---- merge parity partials (fixed-max => plain adds) ----
    if (grp == 1) {
        float* mb = (float*)(lds + wq*5120 + lane*80);
        *(f4v*)(mb)      = acc[0];
        *(f4v*)(mb + 4)  = acc[1];
        *(f4v*)(mb + 8)  = acc[2];
        *(f4v*)(mb + 12) = acc[3];
        *(f4v*)(mb + 16) = lsum;
    }
    __syncthreads();
    if (grp == 0) {
        const float* mb = (const float*)(lds + wq*5120 + lane*80);
        acc[0] += *(const f4v*)(mb);
        acc[1] += *(const f4v*)(mb + 4);
        acc[2] += *(const f4v*)(mb + 8);
        acc[3] += *(const f4v*)(mb + 12);
        lsum   += *(const f4v*)(mb + 16);

        #pragma unroll
        for (int m = 1; m <= 8; m <<= 1) {
            lsum[0] += __shfl_xor(lsum[0], m);
            lsum[1] += __shfl_xor(lsum[1], m);
            lsum[2] += __shfl_xor(lsum[2], m);
            lsum[3] += __shfl_xor(lsum[3], m);
        }

        #pragma unroll
        for (int i = 0; i < 4; i++) {
            const float invl = 1.0f / lsum[i];
            const size_t rowbase = ((size_t)(b*SEQ) + q0 + wq*16 + 4*g + i) * HH + h*HDIM;
            #pragma unroll
            for (int t4 = 0; t4 < 4; t4++)
                CTX[rowbase + 16*t4 + r] = f2bf(acc[t4][i] * invl);
        }
    }
    #undef STAGE
}

// ---------------------------------------------------------------------------
// In-place LayerNorm over rows of 768.
// ---------------------------------------------------------------------------
__global__ __launch_bounds__(256)
void ln_kernel(float* __restrict__ y, const float* __restrict__ gamma,
               const float* __restrict__ beta)
{
    const int row = blockIdx.x;
    float* p = y + (size_t)row * HH;
    const int tid = threadIdx.x;

    float v[3];
    float s = 0.f, ss = 0.f;
    #pragma unroll
    for (int i = 0; i < 3; i++) {
        float x = p[tid + i*256];
        v[i] = x;
        s += x;
        ss += x * x;
    }
    #pragma unroll
    for (int off = 32; off > 0; off >>= 1) {
        s  += __shfl_down(s,  off);
        ss += __shfl_down(ss, off);
    }
    __shared__ float sbuf[4], ssbuf[4];
    __shared__ float mu_s, rstd_s;
    const int wave = tid >> 6;
    if ((tid & 63) == 0) { sbuf[wave] = s; ssbuf[wave] = ss; }
    __syncthreads();
    if (tid == 0) {
        float S  = sbuf[0] + sbuf[1] + sbuf[2] + sbuf[3];
        float SS = ssbuf[0] + ssbuf[1] + ssbuf[2] + ssbuf[3];
        float mu = S * (1.0f / HH);
        float var = SS * (1.0f / HH) - mu * mu;
        mu_s = mu;
        rstd_s = rsqrtf(var + 1e-5f);
    }
    __syncthreads();
    const float mu = mu_s, rstd = rstd_s;
    #pragma unroll
    for (int i = 0; i < 3; i++) {
        const int c = tid + i*256;
        p[c] = (v[i] - mu) * rstd * gamma[c] + beta[c];
    }
}

// ---------------------------------------------------------------------------
extern "C" void kernel_launch(void* const* d_in, const int* in_sizes, int n_in,
                              void* d_out, int out_size, void* d_ws, size_t ws_size,
                              hipStream_t stream)
{
    const float* x     = (const float*)d_in[0];
    const float* mask  = (const float*)d_in[1];
    const float* Wq    = (const float*)d_in[2];
    const float* bq    = (const float*)d_in[3];
    const float* Wk    = (const float*)d_in[4];
    const float* bk    = (const float*)d_in[5];
    const float* Wv    = (const float*)d_in[6];
    const float* bv    = (const float*)d_in[7];
    const float* Wo    = (const float*)d_in[8];
    const float* bo    = (const float*)d_in[9];
    const float* gamma = (const float*)d_in[10];
    const float* beta  = (const float*)d_in[11];

    const size_t PER = (size_t)NB * NHEADS * SEQ * HDIM;
    const size_t WSZ = (size_t)HH * HH;
    short* wsS  = (short*)d_ws;
    short* Xb   = wsS;
    short* VTb  = wsS;
    short* Wqb  = wsS + PER;
    short* Wkb  = Wqb + WSZ;
    short* Wvb  = Wkb + WSZ;
    short* Wob  = Wvb + WSZ;
    short* Qb   = Wob + WSZ;
    short* Kb   = Qb + PER;
    short* Vb   = Kb + PER;
    short* CTXb = Vb;
    float* out  = (float*)d_out;

    cvt_kernel<<<2688, 256, 0, stream>>>(x, Xb, Wq, Wqb, Wk, Wkb, Wv, Wvb, Wo, Wob);

    gemm_mfma<0><<<dim3(18, 32), 256, 0, stream>>>(
        Xb, Wqb, Wkb, Wvb, bq, bk, bv, Qb, Kb, Vb, nullptr, nullptr);

    vtrans_kernel<<<dim3(SEQ/64, NHEADS, NB), 256, 0, stream>>>(Vb, VTb);

    attn_mfma<<<768, 512, 0, stream>>>(Qb, Kb, VTb, mask, CTXb);

    gemm_mfma<1><<<dim3(6, 32), 256, 0, stream>>>(
        CTXb, Wob, nullptr, nullptr, bo, nullptr, nullptr,
        nullptr, nullptr, nullptr, x, out);

    ln_kernel<<<NB*SEQ, 256, 0, stream>>>(out, gamma, beta);
}

// Round 8
// 123.752 us; speedup vs baseline: 1.4904x; 1.0554x over previous
//
#include <hip/hip_runtime.h>
#include <math.h>

#define HH 768
#define NHEADS 12
#define HDIM 64
#define SEQ 2048
#define NB 2
#define L2E 1.44269504088896f

typedef __attribute__((ext_vector_type(8))) short s8v;
typedef __attribute__((ext_vector_type(4))) short s4v;
typedef __attribute__((ext_vector_type(4))) float f4v;

static __device__ inline short f2bf(float f) {
    union { float f; unsigned u; } v; v.f = f;
    unsigned r = v.u + 0x7fff + ((v.u >> 16) & 1);   // RNE
    return (short)(r >> 16);
}

#if __has_builtin(__builtin_amdgcn_exp2f)
#define EXP2(x) __builtin_amdgcn_exp2f(x)
#else
#define EXP2(x) __expf((x) * 0.6931471805599453f)
#endif

__device__ __forceinline__ unsigned cvt_pk_bf16(float a, float b) {
    unsigned r;
    asm("v_cvt_pk_bf16_f32 %0, %1, %2" : "=v"(r) : "v"(a), "v"(b));
    return r;
}

__device__ __forceinline__ void gld16(const void* g, void* l) {
    __builtin_amdgcn_global_load_lds(
        (const __attribute__((address_space(1))) void*)g,
        (__attribute__((address_space(3))) void*)l, 16, 0, 0);
}

// ---------------------------------------------------------------------------
// fp32 -> bf16 conversion: X (4096x768) and the 4 weight matrices (768x768).
// ---------------------------------------------------------------------------
#define XV8   393216
#define WV8   73728
__global__ __launch_bounds__(256)
void cvt_kernel(const float* __restrict__ X, short* __restrict__ Xb,
                const float* __restrict__ W0, short* __restrict__ W0b,
                const float* __restrict__ W1, short* __restrict__ W1b,
                const float* __restrict__ W2, short* __restrict__ W2b,
                const float* __restrict__ W3, short* __restrict__ W3b)
{
    int gid = blockIdx.x * 256 + threadIdx.x;
    const float* src; short* dst; size_t off;
    if      (gid < XV8)            { src = X;  dst = Xb;  off = gid; }
    else if (gid < XV8 + WV8)      { src = W0; dst = W0b; off = gid - XV8; }
    else if (gid < XV8 + 2*WV8)    { src = W1; dst = W1b; off = gid - XV8 - WV8; }
    else if (gid < XV8 + 3*WV8)    { src = W2; dst = W2b; off = gid - XV8 - 2*WV8; }
    else if (gid < XV8 + 4*WV8)    { src = W3; dst = W3b; off = gid - XV8 - 3*WV8; }
    else return;
    off *= 8;
    float4 a = *(const float4*)(src + off);
    float4 b = *(const float4*)(src + off + 4);
    s8v o;
    o[0] = f2bf(a.x); o[1] = f2bf(a.y); o[2] = f2bf(a.z); o[3] = f2bf(a.w);
    o[4] = f2bf(b.x); o[5] = f2bf(b.y); o[6] = f2bf(b.z); o[7] = f2bf(b.w);
    *(s8v*)(dst + off) = o;
}

// ---------------------------------------------------------------------------
// MFMA GEMM, 128x128 tile, BK=32, 4 waves (2x2, 64x64 each).
// EPI 0: fused QKV -> bf16 [B,NH,S,HD], Q scaled by 0.125*log2(e).
// EPI 1: out-proj -> fp32 [4096,768] + bias + residual.
// ---------------------------------------------------------------------------
template<int EPI>
__global__ __launch_bounds__(256)
void gemm_mfma(const short* __restrict__ A,
               const short* __restrict__ Wq, const short* __restrict__ Wk,
               const short* __restrict__ Wv,
               const float* __restrict__ bq, const float* __restrict__ bk,
               const float* __restrict__ bv,
               short* __restrict__ Qo, short* __restrict__ Ko, short* __restrict__ Vo,
               const float* __restrict__ Xres, float* __restrict__ Fo)
{
    __shared__ __align__(16) short As[128*32];
    __shared__ __align__(16) short Bs[128*32];

    const int tid  = threadIdx.x;
    const int w    = tid >> 6;
    const int lane = tid & 63;
    const int g    = lane >> 4;
    const int r    = lane & 15;
    const int wr   = w >> 1;
    const int wc   = w & 1;
    const int m0   = blockIdx.y * 128;

    int n0;
    const short* Wb; const float* bias; short* outp; float scale;
    if (EPI == 0) {
        const int seg = blockIdx.x / 6;
        n0 = (blockIdx.x % 6) * 128;
        Wb   = seg == 0 ? Wq : seg == 1 ? Wk : Wv;
        bias = seg == 0 ? bq : seg == 1 ? bk : bv;
        outp = seg == 0 ? Qo : seg == 1 ? Ko : Vo;
        scale = seg == 0 ? (0.125f * L2E) : 1.0f;
    } else {
        n0 = blockIdx.x * 128;
        Wb = Wq; bias = bq; outp = nullptr; scale = 1.0f;
    }

    const int lrow = lane >> 2;
    const int lcol = (lane & 3) * 8;
    const short* Ag0 = A  + (size_t)(m0 + w*32 + lrow) * HH + lcol;
    const short* Bg0 = Wb + (size_t)(n0 + w*32 + lrow) * HH + lcol;
    short* Al0 = As + (w*32)      * 32;
    short* Al1 = As + (w*32 + 16) * 32;
    short* Bl0 = Bs + (w*32)      * 32;
    short* Bl1 = Bs + (w*32 + 16) * 32;

    f4v acc[4][4];
    #pragma unroll
    for (int i = 0; i < 4; i++)
        #pragma unroll
        for (int j = 0; j < 4; j++) acc[i][j] = (f4v){0.f,0.f,0.f,0.f};

    for (int kt = 0; kt < HH/32; ++kt) {
        const int k0 = kt * 32;
        gld16(Ag0 + k0,           Al0);
        gld16(Ag0 + k0 + 16*HH,   Al1);
        gld16(Bg0 + k0,           Bl0);
        gld16(Bg0 + k0 + 16*HH,   Bl1);
        __syncthreads();

        s8v af[4], bf[4];
        #pragma unroll
        for (int mi = 0; mi < 4; mi++)
            af[mi] = *(const s8v*)(As + (wr*64 + mi*16 + r)*32 + g*8);
        #pragma unroll
        for (int ni = 0; ni < 4; ni++)
            bf[ni] = *(const s8v*)(Bs + (wc*64 + ni*16 + r)*32 + g*8);
        __builtin_amdgcn_s_setprio(1);
        #pragma unroll
        for (int mi = 0; mi < 4; mi++)
            #pragma unroll
            for (int ni = 0; ni < 4; ni++)
                acc[mi][ni] = __builtin_amdgcn_mfma_f32_16x16x32_bf16(af[mi], bf[ni], acc[mi][ni], 0, 0, 0);
        __builtin_amdgcn_s_setprio(0);
        __syncthreads();
    }

    if (EPI == 0) {
        #pragma unroll
        for (int mi = 0; mi < 4; mi++) {
            #pragma unroll
            for (int j = 0; j < 4; j++) {
                const int m = m0 + wr*64 + mi*16 + 4*g + j;
                const int bb = m >> 11;
                const int s  = m & 2047;
                #pragma unroll
                for (int ni = 0; ni < 4; ni++) {
                    const int n = n0 + wc*64 + ni*16 + r;
                    const int h = n >> 6;
                    const int d = n & 63;
                    outp[((size_t)((bb*NHEADS + h)*SEQ) + s)*HDIM + d] =
                        f2bf((acc[mi][ni][j] + bias[n]) * scale);
                }
            }
        }
    } else {
        #pragma unroll
        for (int mi = 0; mi < 4; mi++) {
            #pragma unroll
            for (int j = 0; j < 4; j++) {
                const int m = m0 + wr*64 + mi*16 + 4*g + j;
                #pragma unroll
                for (int ni = 0; ni < 4; ni++) {
                    const int n = n0 + wc*64 + ni*16 + r;
                    Fo[(size_t)m*HH + n] = acc[mi][ni][j] + bias[n] + Xres[(size_t)m*HH + n];
                }
            }
        }
    }
}

// ---------------------------------------------------------------------------
// V [B,NH,S,HD] -> VT [B,NH,HD,S], 64x64 LDS tiles.
// ---------------------------------------------------------------------------
__global__ __launch_bounds__(256)
void vtrans_kernel(const short* __restrict__ V, short* __restrict__ VT)
{
    const int st = blockIdx.x;
    const int h  = blockIdx.y;
    const int b  = blockIdx.z;
    __shared__ short T[64][72];
    const int t = threadIdx.x;
    const short* src = V + ((size_t)(b*NHEADS + h)*SEQ + st*64) * HDIM;

    {
        const int sl = t >> 2;
        const int dq = (t & 3) * 16;
        s8v a = *(const s8v*)(src + sl*HDIM + dq);
        s8v c = *(const s8v*)(src + sl*HDIM + dq + 8);
        #pragma unroll
        for (int i = 0; i < 8; i++) { T[dq+i][sl] = a[i]; T[dq+8+i][sl] = c[i]; }
    }
    __syncthreads();
    {
        const int d  = t >> 2;
        const int sq = (t & 3) * 16;
        s8v o0 = *(const s8v*)&T[d][sq];
        s8v o1 = *(const s8v*)&T[d][sq+8];
        short* dst = VT + ((size_t)(b*NHEADS + h)*HDIM + d)*SEQ + st*64 + sq;
        *(s8v*)(dst)     = o0;
        *(s8v*)(dst + 8) = o1;
    }
}

// ---------------------------------------------------------------------------
// Flash attention, bf16 MFMA, 8 waves / 512 threads, KV-parity split.
// Pair = 64 contiguous k-rows; parity group grp handles a 32-row half.
// Fixed-max exp2 softmax, per-lane deferred l, LDS merge at end.
// LDS 48 KB (K 2x8K dbuf, V 2x8K dbuf, P 16K) -> 3 blocks/CU.
// All tiles use 128-BYTE rows + 3-bit (row&7) XOR slot keys (round-6
// geometry, measured conflict-free); gld16 keeps LDS dest linear and
// pre-applies the involution on the global source column (G21).
// V rows hold BOTH parities: slot j = 4*grp + g covers k = 32*grp + 8g.
// ---------------------------------------------------------------------------
#define NPAIR (SEQ/64)
__global__ __launch_bounds__(512, 4)
void attn_mfma(const short* __restrict__ Q, const short* __restrict__ K,
               const short* __restrict__ VT, const float* __restrict__ mask,
               short* __restrict__ CTX)
{
    // XCD swizzle: 768 blocks = 8 XCDs x 96; contiguous 96-chunk per XCD
    const int wgid = (blockIdx.x & 7) * 96 + (blockIdx.x >> 3);
    const int qt = wgid & 31;
    const int bh = wgid >> 5;          // 0..23
    const int h  = bh % NHEADS;
    const int b  = bh / NHEADS;

    const size_t hb = (size_t)(b * NHEADS + h);
    const short* Qg  = Q  + hb * SEQ * HDIM;
    const short* Kg  = K  + hb * SEQ * HDIM;
    const short* VTg = VT + hb * HDIM * SEQ;

    __shared__ __align__(16) char lds[49152];
    char* Kbase = lds;            // [2 db][64 k-rows][128B]
    char* Vbase = lds + 16384;    // [2 db][64 d-rows][128B] (both parities/row)
    char* Pbase = lds + 32768;    // [8 waves][16 q-rows][128B]

    const int tid  = threadIdx.x;
    const int w    = tid >> 6;
    const int grp  = w >> 2;      // parity: which 32-row half of the pair
    const int wq   = w & 3;       // q-subtile owner
    const int lane = tid & 63;
    const int g    = lane >> 4;
    const int r    = lane & 15;
    const int q0   = qt * 64;

    const short* qrow = Qg + (size_t)(q0 + wq*16 + r) * HDIM;
    const s8v qf0 = *(const s8v*)(qrow + 8*g);
    const s8v qf1 = *(const s8v*)(qrow + 8*g + 32);

    f4v acc[4];
    #pragma unroll
    for (int t = 0; t < 4; t++) acc[t] = (f4v){0.f, 0.f, 0.f, 0.f};
    f4v lsum = (f4v){0.f, 0.f, 0.f, 0.f};

    // staging: one gld16 per thread per matrix; LDS dest linear
    // (wave-uniform base + lane*16), source column pre-swizzled.
    const int srow = lane >> 3;                        // row-within-wave-chunk & row&7 key
    const int scol = 8 * ((lane & 7) ^ srow);          // pre-swizzled col (elems)

    #define STAGE(PT, DB) do {                                                 \
        const int pk0 = (PT) * 64;                                             \
        char* kd = Kbase + (DB)*8192 + w*1024;                                 \
        gld16(Kg + (size_t)(pk0 + 8*w + srow)*HDIM + scol, kd);                \
        char* vd = Vbase + (DB)*8192 + w*1024;                                 \
        gld16(VTg + (size_t)(8*w + srow)*SEQ + pk0 + scol, vd);                \
    } while (0)

    STAGE(0, 0);
    __syncthreads();

    char* pb = Pbase + w*2048;

    for (int pt = 0; pt < NPAIR; ++pt) {
        const int db = pt & 1;
        if (pt + 1 < NPAIR) STAGE(pt + 1, db ^ 1);   // async, drained at barrier

        const char* Kc = Kbase + db*8192 + grp*4096; // 32 k-rows x 128B
        const char* Vc = Vbase + db*8192;            // 64 d-rows x 128B
        const int k0 = pt*64 + grp*32;

        float madd[2];
        madd[0] = (mask[b*SEQ + k0 + r]      - 1.0f) * (10000.0f * L2E);
        madd[1] = (mask[b*SEQ + k0 + 16 + r] - 1.0f) * (10000.0f * L2E);

        // ---- QK^T (log2-space scores), k-extent 32 ----
        f4v sj[2];
        __builtin_amdgcn_s_setprio(1);
        #pragma unroll
        for (int j = 0; j < 2; j++) {
            const int krow = 16*j + r;
            const char* kb = Kc + krow * 128;
            const int sw = (r & 7) << 4;             // krow&7 == r&7
            s8v kf0 = *(const s8v*)(kb + ((16*g)      ^ sw));
            s8v kf1 = *(const s8v*)(kb + ((16*g + 64) ^ sw));
            f4v z = (f4v){0.f, 0.f, 0.f, 0.f};
            z = __builtin_amdgcn_mfma_f32_16x16x32_bf16(qf0, kf0, z, 0, 0, 0);
            z = __builtin_amdgcn_mfma_f32_16x16x32_bf16(qf1, kf1, z, 0, 0, 0);
            #pragma unroll
            for (int i = 0; i < 4; i++) z[i] += madd[j];
            sj[j] = z;
        }
        __builtin_amdgcn_s_setprio(0);

        // ---- p = exp2(s), per-lane l partials ----
        #pragma unroll
        for (int j = 0; j < 2; j++)
            #pragma unroll
            for (int i = 0; i < 4; i++)
                sj[j][i] = EXP2(sj[j][i]);
        #pragma unroll
        for (int i = 0; i < 4; i++)
            lsum[i] += sj[0][i] + sj[1][i];

        // ---- P -> bf16 -> per-wave LDS (128B rows, (row&7) slot key) ----
        #pragma unroll
        for (int i = 0; i < 4; i++) {
            const int prow = 4*g + i;
            char* base = pb + prow * 128;
            const int sw = (prow & 7) << 4;
            unsigned u = cvt_pk_bf16(sj[0][i], sj[1][i]);
            *(short*)(base + ((r*2)        ^ sw)) = (short)(u & 0xffff);
            *(short*)(base + ((32 + r*2)   ^ sw)) = (short)(u >> 16);
        }

        // ---- ctx += P @ V (k-extent 32; V slot = 4*grp+g) ----
        __builtin_amdgcn_s_setprio(1);
        {
            s8v pf = *(const s8v*)(pb + r*128 + ((16*g) ^ ((r & 7) << 4)));
            #pragma unroll
            for (int t4 = 0; t4 < 4; t4++) {
                const int vrow = 16*t4 + r;
                s8v vf = *(const s8v*)(Vc + vrow*128 + ((16*(4*grp + g)) ^ ((r & 7) << 4)));
                acc[t4] = __builtin_amdgcn_mfma_f32_16x16x32_bf16(pf, vf, acc[t4], 0, 0, 0);
            }
        }
        __builtin_amdgcn_s_setprio(0);

        __syncthreads();   // drains prefetch vmcnt; next pair ready, bufs free
    }

    // ---- merge parity partials (fixed-max => plain adds) ----
    if (grp == 1) {
        float* mb = (float*)(lds + wq*5120 + lane*80);
        *(f4v*)(mb)      = acc[0];
        *(f4v*)(mb + 4)  = acc[1];
        *(f4v*)(mb + 8)  = acc[2];
        *(f4v*)(mb + 12) = acc[3];
        *(f4v*)(mb + 16) = lsum;
    }
    __syncthreads();
    if (grp == 0) {
        const float* mb = (const float*)(lds + wq*5120 + lane*80);
        acc[0] += *(const f4v*)(mb);
        acc[1] += *(const f4v*)(mb + 4);
        acc[2] += *(const f4v*)(mb + 8);
        acc[3] += *(const f4v*)(mb + 12);
        lsum   += *(const f4v*)(mb + 16);

        #pragma unroll
        for (int m = 1; m <= 8; m <<= 1) {
            lsum[0] += __shfl_xor(lsum[0], m);
            lsum[1] += __shfl_xor(lsum[1], m);
            lsum[2] += __shfl_xor(lsum[2], m);
            lsum[3] += __shfl_xor(lsum[3], m);
        }

        #pragma unroll
        for (int i = 0; i < 4; i++) {
            const float invl = 1.0f / lsum[i];
            const size_t rowbase = ((size_t)(b*SEQ) + q0 + wq*16 + 4*g + i) * HH + h*HDIM;
            #pragma unroll
            for (int t4 = 0; t4 < 4; t4++)
                CTX[rowbase + 16*t4 + r] = f2bf(acc[t4][i] * invl);
        }
    }
    #undef STAGE
}

// ---------------------------------------------------------------------------
// In-place LayerNorm over rows of 768.
// ---------------------------------------------------------------------------
__global__ __launch_bounds__(256)
void ln_kernel(float* __restrict__ y, const float* __restrict__ gamma,
               const float* __restrict__ beta)
{
    const int row = blockIdx.x;
    float* p = y + (size_t)row * HH;
    const int tid = threadIdx.x;

    float v[3];
    float s = 0.f, ss = 0.f;
    #pragma unroll
    for (int i = 0; i < 3; i++) {
        float x = p[tid + i*256];
        v[i] = x;
        s += x;
        ss += x * x;
    }
    #pragma unroll
    for (int off = 32; off > 0; off >>= 1) {
        s  += __shfl_down(s,  off);
        ss += __shfl_down(ss, off);
    }
    __shared__ float sbuf[4], ssbuf[4];
    __shared__ float mu_s, rstd_s;
    const int wave = tid >> 6;
    if ((tid & 63) == 0) { sbuf[wave] = s; ssbuf[wave] = ss; }
    __syncthreads();
    if (tid == 0) {
        float S  = sbuf[0] + sbuf[1] + sbuf[2] + sbuf[3];
        float SS = ssbuf[0] + ssbuf[1] + ssbuf[2] + ssbuf[3];
        float mu = S * (1.0f / HH);
        float var = SS * (1.0f / HH) - mu * mu;
        mu_s = mu;
        rstd_s = rsqrtf(var + 1e-5f);
    }
    __syncthreads();
    const float mu = mu_s, rstd = rstd_s;
    #pragma unroll
    for (int i = 0; i < 3; i++) {
        const int c = tid + i*256;
        p[c] = (v[i] - mu) * rstd * gamma[c] + beta[c];
    }
}

// ---------------------------------------------------------------------------
extern "C" void kernel_launch(void* const* d_in, const int* in_sizes, int n_in,
                              void* d_out, int out_size, void* d_ws, size_t ws_size,
                              hipStream_t stream)
{
    const float* x     = (const float*)d_in[0];
    const float* mask  = (const float*)d_in[1];
    const float* Wq    = (const float*)d_in[2];
    const float* bq    = (const float*)d_in[3];
    const float* Wk    = (const float*)d_in[4];
    const float* bk    = (const float*)d_in[5];
    const float* Wv    = (const float*)d_in[6];
    const float* bv    = (const float*)d_in[7];
    const float* Wo    = (const float*)d_in[8];
    const float* bo    = (const float*)d_in[9];
    const float* gamma = (const float*)d_in[10];
    const float* beta  = (const float*)d_in[11];

    const size_t PER = (size_t)NB * NHEADS * SEQ * HDIM;
    const size_t WSZ = (size_t)HH * HH;
    short* wsS  = (short*)d_ws;
    short* Xb   = wsS;
    short* VTb  = wsS;
    short* Wqb  = wsS + PER;
    short* Wkb  = Wqb + WSZ;
    short* Wvb  = Wkb + WSZ;
    short* Wob  = Wvb + WSZ;
    short* Qb   = Wob + WSZ;
    short* Kb   = Qb + PER;
    short* Vb   = Kb + PER;
    short* CTXb = Vb;
    float* out  = (float*)d_out;

    cvt_kernel<<<2688, 256, 0, stream>>>(x, Xb, Wq, Wqb, Wk, Wkb, Wv, Wvb, Wo, Wob);

    gemm_mfma<0><<<dim3(18, 32), 256, 0, stream>>>(
        Xb, Wqb, Wkb, Wvb, bq, bk, bv, Qb, Kb, Vb, nullptr, nullptr);

    vtrans_kernel<<<dim3(SEQ/64, NHEADS, NB), 256, 0, stream>>>(Vb, VTb);

    attn_mfma<<<768, 512, 0, stream>>>(Qb, Kb, VTb, mask, CTXb);

    gemm_mfma<1><<<dim3(6, 32), 256, 0, stream>>>(
        CTXb, Wob, nullptr, nullptr, bo, nullptr, nullptr,
        nullptr, nullptr, nullptr, x, out);

    ln_kernel<<<NB*SEQ, 256, 0, stream>>>(out, gamma, beta);
}

// Round 9
// 121.319 us; speedup vs baseline: 1.5203x; 1.0201x over previous
//
#include <hip/hip_runtime.h>
#include <math.h>

#define HH 768
#define NHEADS 12
#define HDIM 64
#define SEQ 2048
#define NB 2
#define L2E 1.44269504088896f

typedef __attribute__((ext_vector_type(8))) short s8v;
typedef __attribute__((ext_vector_type(4))) short s4v;
typedef __attribute__((ext_vector_type(4))) float f4v;

static __device__ inline short f2bf(float f) {
    union { float f; unsigned u; } v; v.f = f;
    unsigned r = v.u + 0x7fff + ((v.u >> 16) & 1);   // RNE
    return (short)(r >> 16);
}

#if __has_builtin(__builtin_amdgcn_exp2f)
#define EXP2(x) __builtin_amdgcn_exp2f(x)
#else
#define EXP2(x) __expf((x) * 0.6931471805599453f)
#endif

__device__ __forceinline__ unsigned cvt_pk_bf16(float a, float b) {
    unsigned r;
    asm("v_cvt_pk_bf16_f32 %0, %1, %2" : "=v"(r) : "v"(a), "v"(b));
    return r;
}

__device__ __forceinline__ void gld16(const void* g, void* l) {
    __builtin_amdgcn_global_load_lds(
        (const __attribute__((address_space(1))) void*)g,
        (__attribute__((address_space(3))) void*)l, 16, 0, 0);
}

// ---------------------------------------------------------------------------
// fp32 -> bf16 conversion: X (4096x768) and the 4 weight matrices (768x768).
// ---------------------------------------------------------------------------
#define XV8   393216
#define WV8   73728
__global__ __launch_bounds__(256)
void cvt_kernel(const float* __restrict__ X, short* __restrict__ Xb,
                const float* __restrict__ W0, short* __restrict__ W0b,
                const float* __restrict__ W1, short* __restrict__ W1b,
                const float* __restrict__ W2, short* __restrict__ W2b,
                const float* __restrict__ W3, short* __restrict__ W3b)
{
    int gid = blockIdx.x * 256 + threadIdx.x;
    const float* src; short* dst; size_t off;
    if      (gid < XV8)            { src = X;  dst = Xb;  off = gid; }
    else if (gid < XV8 + WV8)      { src = W0; dst = W0b; off = gid - XV8; }
    else if (gid < XV8 + 2*WV8)    { src = W1; dst = W1b; off = gid - XV8 - WV8; }
    else if (gid < XV8 + 3*WV8)    { src = W2; dst = W2b; off = gid - XV8 - 2*WV8; }
    else if (gid < XV8 + 4*WV8)    { src = W3; dst = W3b; off = gid - XV8 - 3*WV8; }
    else return;
    off *= 8;
    float4 a = *(const float4*)(src + off);
    float4 b = *(const float4*)(src + off + 4);
    s8v o;
    o[0] = f2bf(a.x); o[1] = f2bf(a.y); o[2] = f2bf(a.z); o[3] = f2bf(a.w);
    o[4] = f2bf(b.x); o[5] = f2bf(b.y); o[6] = f2bf(b.z); o[7] = f2bf(b.w);
    *(s8v*)(dst + off) = o;
}

// ---------------------------------------------------------------------------
// MFMA GEMM, 128x128 tile, BK=32, 4 waves (2x2, 64x64 each).
// EPI 0: fused QKV. seg 0/1 -> bf16 [B,NH,S,HD] (Q scaled by 0.125*log2e);
//        seg 2 (V) -> bf16 V^T [B,NH,HD,S] written directly.
// EPI 1: out-proj -> fp32 [4096,768] + bias + residual.
// ---------------------------------------------------------------------------
template<int EPI>
__global__ __launch_bounds__(256)
void gemm_mfma(const short* __restrict__ A,
               const short* __restrict__ Wq, const short* __restrict__ Wk,
               const short* __restrict__ Wv,
               const float* __restrict__ bq, const float* __restrict__ bk,
               const float* __restrict__ bv,
               short* __restrict__ Qo, short* __restrict__ Ko, short* __restrict__ Vo,
               const float* __restrict__ Xres, float* __restrict__ Fo)
{
    __shared__ __align__(16) short As[128*32];
    __shared__ __align__(16) short Bs[128*32];

    const int tid  = threadIdx.x;
    const int w    = tid >> 6;
    const int lane = tid & 63;
    const int g    = lane >> 4;
    const int r    = lane & 15;
    const int wr   = w >> 1;
    const int wc   = w & 1;
    const int m0   = blockIdx.y * 128;

    int n0;
    int seg = 0;
    const short* Wb; const float* bias; short* outp; float scale;
    if (EPI == 0) {
        seg = blockIdx.x / 6;
        n0 = (blockIdx.x % 6) * 128;
        Wb   = seg == 0 ? Wq : seg == 1 ? Wk : Wv;
        bias = seg == 0 ? bq : seg == 1 ? bk : bv;
        outp = seg == 0 ? Qo : seg == 1 ? Ko : Vo;
        scale = seg == 0 ? (0.125f * L2E) : 1.0f;
    } else {
        n0 = blockIdx.x * 128;
        Wb = Wq; bias = bq; outp = nullptr; scale = 1.0f;
    }

    const int lrow = lane >> 2;
    const int lcol = (lane & 3) * 8;
    const short* Ag0 = A  + (size_t)(m0 + w*32 + lrow) * HH + lcol;
    const short* Bg0 = Wb + (size_t)(n0 + w*32 + lrow) * HH + lcol;
    short* Al0 = As + (w*32)      * 32;
    short* Al1 = As + (w*32 + 16) * 32;
    short* Bl0 = Bs + (w*32)      * 32;
    short* Bl1 = Bs + (w*32 + 16) * 32;

    f4v acc[4][4];
    #pragma unroll
    for (int i = 0; i < 4; i++)
        #pragma unroll
        for (int j = 0; j < 4; j++) acc[i][j] = (f4v){0.f,0.f,0.f,0.f};

    for (int kt = 0; kt < HH/32; ++kt) {
        const int k0 = kt * 32;
        gld16(Ag0 + k0,           Al0);
        gld16(Ag0 + k0 + 16*HH,   Al1);
        gld16(Bg0 + k0,           Bl0);
        gld16(Bg0 + k0 + 16*HH,   Bl1);
        __syncthreads();

        s8v af[4], bf[4];
        #pragma unroll
        for (int mi = 0; mi < 4; mi++)
            af[mi] = *(const s8v*)(As + (wr*64 + mi*16 + r)*32 + g*8);
        #pragma unroll
        for (int ni = 0; ni < 4; ni++)
            bf[ni] = *(const s8v*)(Bs + (wc*64 + ni*16 + r)*32 + g*8);
        __builtin_amdgcn_s_setprio(1);
        #pragma unroll
        for (int mi = 0; mi < 4; mi++)
            #pragma unroll
            for (int ni = 0; ni < 4; ni++)
                acc[mi][ni] = __builtin_amdgcn_mfma_f32_16x16x32_bf16(af[mi], bf[ni], acc[mi][ni], 0, 0, 0);
        __builtin_amdgcn_s_setprio(0);
        __syncthreads();
    }

    if (EPI == 0) {
        if (seg < 2) {
            #pragma unroll
            for (int mi = 0; mi < 4; mi++) {
                #pragma unroll
                for (int j = 0; j < 4; j++) {
                    const int m = m0 + wr*64 + mi*16 + 4*g + j;
                    const int bb = m >> 11;
                    const int s  = m & 2047;
                    #pragma unroll
                    for (int ni = 0; ni < 4; ni++) {
                        const int n = n0 + wc*64 + ni*16 + r;
                        const int h = n >> 6;
                        const int d = n & 63;
                        outp[((size_t)((bb*NHEADS + h)*SEQ) + s)*HDIM + d] =
                            f2bf((acc[mi][ni][j] + bias[n]) * scale);
                    }
                }
            }
        } else {
            // V^T direct: thread packs 4 contiguous s for its d-row
            #pragma unroll
            for (int mi = 0; mi < 4; mi++) {
                const int m  = m0 + wr*64 + mi*16 + 4*g;   // j=0 base, 4-aligned
                const int bb = m >> 11;
                const int s  = m & 2047;
                #pragma unroll
                for (int ni = 0; ni < 4; ni++) {
                    const int n = n0 + wc*64 + ni*16 + r;
                    const int h = n >> 6;
                    const int d = n & 63;
                    s4v pk;
                    #pragma unroll
                    for (int j = 0; j < 4; j++)
                        pk[j] = f2bf(acc[mi][ni][j] + bias[n]);
                    *(s4v*)(outp + ((size_t)((bb*NHEADS + h)*HDIM) + d)*SEQ + s) = pk;
                }
            }
        }
    } else {
        #pragma unroll
        for (int mi = 0; mi < 4; mi++) {
            #pragma unroll
            for (int j = 0; j < 4; j++) {
                const int m = m0 + wr*64 + mi*16 + 4*g + j;
                #pragma unroll
                for (int ni = 0; ni < 4; ni++) {
                    const int n = n0 + wc*64 + ni*16 + r;
                    Fo[(size_t)m*HH + n] = acc[mi][ni][j] + bias[n] + Xres[(size_t)m*HH + n];
                }
            }
        }
    }
}

// ---------------------------------------------------------------------------
// Flash attention, bf16 MFMA, 8 waves / 512 threads, KV-parity split.
// Mask preloaded into LDS as bf16 madd -> K-loop has ZERO global loads
// besides the 2 async gld16 staging ops (vmcnt drained only at barrier).
// Fixed-max exp2 softmax, per-lane deferred l, LDS merge at end.
// LDS 52 KB (K 2x8K, V 2x8K, P 16K, mask 4K) -> 3 blocks/CU.
// 128-byte rows + (row&7) XOR slot keys everywhere (conflict-free, r6/r8).
// ---------------------------------------------------------------------------
#define NPAIR (SEQ/64)
__global__ __launch_bounds__(512, 4)
void attn_mfma(const short* __restrict__ Q, const short* __restrict__ K,
               const short* __restrict__ VT, const float* __restrict__ mask,
               short* __restrict__ CTX)
{
    // XCD swizzle: 768 blocks = 8 XCDs x 96; contiguous 96-chunk per XCD
    const int wgid = (blockIdx.x & 7) * 96 + (blockIdx.x >> 3);
    const int qt = wgid & 31;
    const int bh = wgid >> 5;          // 0..23
    const int h  = bh % NHEADS;
    const int b  = bh / NHEADS;

    const size_t hb = (size_t)(b * NHEADS + h);
    const short* Qg  = Q  + hb * SEQ * HDIM;
    const short* Kg  = K  + hb * SEQ * HDIM;
    const short* VTg = VT + hb * HDIM * SEQ;

    __shared__ __align__(16) char lds[53248];
    char* Kbase = lds;            // [2 db][64 k-rows][128B]
    char* Vbase = lds + 16384;    // [2 db][64 d-rows][128B] (both parities/row)
    char* Pbase = lds + 32768;    // [8 waves][16 q-rows][128B]
    short* Mls  = (short*)(lds + 49152);   // [2048] bf16 madd

    const int tid  = threadIdx.x;
    const int w    = tid >> 6;
    const int grp  = w >> 2;      // parity: which 32-row half of the pair
    const int wq   = w & 3;       // q-subtile owner
    const int lane = tid & 63;
    const int g    = lane >> 4;
    const int r    = lane & 15;
    const int q0   = qt * 64;

    const short* qrow = Qg + (size_t)(q0 + wq*16 + r) * HDIM;
    const s8v qf0 = *(const s8v*)(qrow + 8*g);
    const s8v qf1 = *(const s8v*)(qrow + 8*g + 32);

    // one-time mask -> LDS bf16 madd (512 threads x 4 entries)
    {
        float4 mv = *(const float4*)(mask + b*SEQ + tid*4);
        s4v md;
        md[0] = f2bf((mv.x - 1.0f) * (10000.0f * L2E));
        md[1] = f2bf((mv.y - 1.0f) * (10000.0f * L2E));
        md[2] = f2bf((mv.z - 1.0f) * (10000.0f * L2E));
        md[3] = f2bf((mv.w - 1.0f) * (10000.0f * L2E));
        *(s4v*)(Mls + tid*4) = md;
    }

    f4v acc[4];
    #pragma unroll
    for (int t = 0; t < 4; t++) acc[t] = (f4v){0.f, 0.f, 0.f, 0.f};
    f4v lsum = (f4v){0.f, 0.f, 0.f, 0.f};

    // staging: one gld16 per thread per matrix; LDS dest linear,
    // source column pre-swizzled (G21 both-sides involution).
    const int srow = lane >> 3;
    const int scol = 8 * ((lane & 7) ^ srow);

    #define STAGE(PT, DB) do {                                                 \
        const int pk0 = (PT) * 64;                                             \
        char* kd = Kbase + (DB)*8192 + w*1024;                                 \
        gld16(Kg + (size_t)(pk0 + 8*w + srow)*HDIM + scol, kd);                \
        char* vd = Vbase + (DB)*8192 + w*1024;                                 \
        gld16(VTg + (size_t)(8*w + srow)*SEQ + pk0 + scol, vd);                \
    } while (0)

    STAGE(0, 0);
    __syncthreads();   // covers staging AND the mask preload

    char* pb = Pbase + w*2048;

    for (int pt = 0; pt < NPAIR; ++pt) {
        const int db = pt & 1;
        if (pt + 1 < NPAIR) STAGE(pt + 1, db ^ 1);   // async, drained at barrier

        const char* Kc = Kbase + db*8192 + grp*4096; // 32 k-rows x 128B
        const char* Vc = Vbase + db*8192;            // 64 d-rows x 128B
        const int k0 = pt*64 + grp*32;

        float madd[2];
        {
            union { unsigned u; float f; } c0, c1;
            c0.u = ((unsigned)(unsigned short)Mls[k0 + r])      << 16;
            c1.u = ((unsigned)(unsigned short)Mls[k0 + 16 + r]) << 16;
            madd[0] = c0.f;
            madd[1] = c1.f;
        }

        // ---- QK^T (log2-space scores), k-extent 32 ----
        f4v sj[2];
        __builtin_amdgcn_s_setprio(1);
        #pragma unroll
        for (int j = 0; j < 2; j++) {
            const int krow = 16*j + r;
            const char* kb = Kc + krow * 128;
            const int sw = (r & 7) << 4;             // krow&7 == r&7
            s8v kf0 = *(const s8v*)(kb + ((16*g)      ^ sw));
            s8v kf1 = *(const s8v*)(kb + ((16*g + 64) ^ sw));
            f4v z = (f4v){0.f, 0.f, 0.f, 0.f};
            z = __builtin_amdgcn_mfma_f32_16x16x32_bf16(qf0, kf0, z, 0, 0, 0);
            z = __builtin_amdgcn_mfma_f32_16x16x32_bf16(qf1, kf1, z, 0, 0, 0);
            #pragma unroll
            for (int i = 0; i < 4; i++) z[i] += madd[j];
            sj[j] = z;
        }
        __builtin_amdgcn_s_setprio(0);

        // ---- p = exp2(s), per-lane l partials ----
        #pragma unroll
        for (int j = 0; j < 2; j++)
            #pragma unroll
            for (int i = 0; i < 4; i++)
                sj[j][i] = EXP2(sj[j][i]);
        #pragma unroll
        for (int i = 0; i < 4; i++)
            lsum[i] += sj[0][i] + sj[1][i];

        // ---- P -> bf16 -> per-wave LDS (128B rows, (row&7) slot key) ----
        #pragma unroll
        for (int i = 0; i < 4; i++) {
            const int prow = 4*g + i;
            char* base = pb + prow * 128;
            const int sw = (prow & 7) << 4;
            unsigned u = cvt_pk_bf16(sj[0][i], sj[1][i]);
            *(short*)(base + ((r*2)        ^ sw)) = (short)(u & 0xffff);
            *(short*)(base + ((32 + r*2)   ^ sw)) = (short)(u >> 16);
        }

        // ---- ctx += P @ V (k-extent 32; V slot = 4*grp+g) ----
        __builtin_amdgcn_s_setprio(1);
        {
            s8v pf = *(const s8v*)(pb + r*128 + ((16*g) ^ ((r & 7) << 4)));
            #pragma unroll
            for (int t4 = 0; t4 < 4; t4++) {
                const int vrow = 16*t4 + r;
                s8v vf = *(const s8v*)(Vc + vrow*128 + ((16*(4*grp + g)) ^ ((r & 7) << 4)));
                acc[t4] = __builtin_amdgcn_mfma_f32_16x16x32_bf16(pf, vf, acc[t4], 0, 0, 0);
            }
        }
        __builtin_amdgcn_s_setprio(0);

        __syncthreads();   // drains prefetch vmcnt; next pair ready, bufs free
    }

    // ---- merge parity partials (fixed-max => plain adds) ----
    if (grp == 1) {
        float* mb = (float*)(lds + wq*5120 + lane*80);
        *(f4v*)(mb)      = acc[0];
        *(f4v*)(mb + 4)  = acc[1];
        *(f4v*)(mb + 8)  = acc[2];
        *(f4v*)(mb + 12) = acc[3];
        *(f4v*)(mb + 16) = lsum;
    }
    __syncthreads();
    if (grp == 0) {
        const float* mb = (const float*)(lds + wq*5120 + lane*80);
        acc[0] += *(const f4v*)(mb);
        acc[1] += *(const f4v*)(mb + 4);
        acc[2] += *(const f4v*)(mb + 8);
        acc[3] += *(const f4v*)(mb + 12);
        lsum   += *(const f4v*)(mb + 16);

        #pragma unroll
        for (int m = 1; m <= 8; m <<= 1) {
            lsum[0] += __shfl_xor(lsum[0], m);
            lsum[1] += __shfl_xor(lsum[1], m);
            lsum[2] += __shfl_xor(lsum[2], m);
            lsum[3] += __shfl_xor(lsum[3], m);
        }

        #pragma unroll
        for (int i = 0; i < 4; i++) {
            const float invl = 1.0f / lsum[i];
            const size_t rowbase = ((size_t)(b*SEQ) + q0 + wq*16 + 4*g + i) * HH + h*HDIM;
            #pragma unroll
            for (int t4 = 0; t4 < 4; t4++)
                CTX[rowbase + 16*t4 + r] = f2bf(acc[t4][i] * invl);
        }
    }
    #undef STAGE
}

// ---------------------------------------------------------------------------
// In-place LayerNorm over rows of 768.
// ---------------------------------------------------------------------------
__global__ __launch_bounds__(256)
void ln_kernel(float* __restrict__ y, const float* __restrict__ gamma,
               const float* __restrict__ beta)
{
    const int row = blockIdx.x;
    float* p = y + (size_t)row * HH;
    const int tid = threadIdx.x;

    float v[3];
    float s = 0.f, ss = 0.f;
    #pragma unroll
    for (int i = 0; i < 3; i++) {
        float x = p[tid + i*256];
        v[i] = x;
        s += x;
        ss += x * x;
    }
    #pragma unroll
    for (int off = 32; off > 0; off >>= 1) {
        s  += __shfl_down(s,  off);
        ss += __shfl_down(ss, off);
    }
    __shared__ float sbuf[4], ssbuf[4];
    __shared__ float mu_s, rstd_s;
    const int wave = tid >> 6;
    if ((tid & 63) == 0) { sbuf[wave] = s; ssbuf[wave] = ss; }
    __syncthreads();
    if (tid == 0) {
        float S  = sbuf[0] + sbuf[1] + sbuf[2] + sbuf[3];
        float SS = ssbuf[0] + ssbuf[1] + ssbuf[2] + ssbuf[3];
        float mu = S * (1.0f / HH);
        float var = SS * (1.0f / HH) - mu * mu;
        mu_s = mu;
        rstd_s = rsqrtf(var + 1e-5f);
    }
    __syncthreads();
    const float mu = mu_s, rstd = rstd_s;
    #pragma unroll
    for (int i = 0; i < 3; i++) {
        const int c = tid + i*256;
        p[c] = (v[i] - mu) * rstd * gamma[c] + beta[c];
    }
}

// ---------------------------------------------------------------------------
extern "C" void kernel_launch(void* const* d_in, const int* in_sizes, int n_in,
                              void* d_out, int out_size, void* d_ws, size_t ws_size,
                              hipStream_t stream)
{
    const float* x     = (const float*)d_in[0];
    const float* mask  = (const float*)d_in[1];
    const float* Wq    = (const float*)d_in[2];
    const float* bq    = (const float*)d_in[3];
    const float* Wk    = (const float*)d_in[4];
    const float* bk    = (const float*)d_in[5];
    const float* Wv    = (const float*)d_in[6];
    const float* bv    = (const float*)d_in[7];
    const float* Wo    = (const float*)d_in[8];
    const float* bo    = (const float*)d_in[9];
    const float* gamma = (const float*)d_in[10];
    const float* beta  = (const float*)d_in[11];

    const size_t PER = (size_t)NB * NHEADS * SEQ * HDIM;
    const size_t WSZ = (size_t)HH * HH;
    short* wsS  = (short*)d_ws;
    short* Xb   = wsS;          // dead after QKV GEMM -> reused as CTXb
    short* Wqb  = wsS + PER;
    short* Wkb  = Wqb + WSZ;
    short* Wvb  = Wkb + WSZ;
    short* Wob  = Wvb + WSZ;
    short* Qb   = Wob + WSZ;
    short* Kb   = Qb + PER;
    short* VTb  = Kb + PER;     // V^T written directly by the GEMM
    short* CTXb = Xb;
    float* out  = (float*)d_out;

    cvt_kernel<<<2688, 256, 0, stream>>>(x, Xb, Wq, Wqb, Wk, Wkb, Wv, Wvb, Wo, Wob);

    gemm_mfma<0><<<dim3(18, 32), 256, 0, stream>>>(
        Xb, Wqb, Wkb, Wvb, bq, bk, bv, Qb, Kb, VTb, nullptr, nullptr);

    attn_mfma<<<768, 512, 0, stream>>>(Qb, Kb, VTb, mask, CTXb);

    gemm_mfma<1><<<dim3(6, 32), 256, 0, stream>>>(
        CTXb, Wob, nullptr, nullptr, bo, nullptr, nullptr,
        nullptr, nullptr, nullptr, x, out);

    ln_kernel<<<NB*SEQ, 256, 0, stream>>>(out, gamma, beta);
}

// Round 10
// 111.427 us; speedup vs baseline: 1.6553x; 1.0888x over previous
//
#include <hip/hip_runtime.h>
#include <math.h>

#define HH 768
#define NHEADS 12
#define HDIM 64
#define SEQ 2048
#define NB 2
#define L2E 1.44269504088896f

typedef __attribute__((ext_vector_type(8))) short s8v;
typedef __attribute__((ext_vector_type(4))) short s4v;
typedef __attribute__((ext_vector_type(4))) float f4v;

static __device__ inline short f2bf(float f) {
    union { float f; unsigned u; } v; v.f = f;
    unsigned r = v.u + 0x7fff + ((v.u >> 16) & 1);   // RNE
    return (short)(r >> 16);
}

#if __has_builtin(__builtin_amdgcn_exp2f)
#define EXP2(x) __builtin_amdgcn_exp2f(x)
#else
#define EXP2(x) __expf((x) * 0.6931471805599453f)
#endif

__device__ __forceinline__ unsigned cvt_pk_bf16(float a, float b) {
    unsigned r;
    asm("v_cvt_pk_bf16_f32 %0, %1, %2" : "=v"(r) : "v"(a), "v"(b));
    return r;
}

__device__ __forceinline__ void gld16(const void* g, void* l) {
    __builtin_amdgcn_global_load_lds(
        (const __attribute__((address_space(1))) void*)g,
        (__attribute__((address_space(3))) void*)l, 16, 0, 0);
}

// k-position permutation within each 32-group (shared by V^T layout, mask
// layout, and the PV MFMA slot order): pos = 8*((k>>2)&3) + 4*((k>>4)&1) + (k&3)
__device__ __forceinline__ int kperm(int k) {
    return (k & ~31) | (((k >> 2) & 3) << 3) | (((k >> 4) & 1) << 2) | (k & 3);
}

// ---------------------------------------------------------------------------
// fp32 -> bf16 conversion: X (4096x768) and the 4 weight matrices (768x768).
// ---------------------------------------------------------------------------
#define XV8   393216
#define WV8   73728
__global__ __launch_bounds__(256)
void cvt_kernel(const float* __restrict__ X, short* __restrict__ Xb,
                const float* __restrict__ W0, short* __restrict__ W0b,
                const float* __restrict__ W1, short* __restrict__ W1b,
                const float* __restrict__ W2, short* __restrict__ W2b,
                const float* __restrict__ W3, short* __restrict__ W3b)
{
    int gid = blockIdx.x * 256 + threadIdx.x;
    const float* src; short* dst; size_t off;
    if      (gid < XV8)            { src = X;  dst = Xb;  off = gid; }
    else if (gid < XV8 + WV8)      { src = W0; dst = W0b; off = gid - XV8; }
    else if (gid < XV8 + 2*WV8)    { src = W1; dst = W1b; off = gid - XV8 - WV8; }
    else if (gid < XV8 + 3*WV8)    { src = W2; dst = W2b; off = gid - XV8 - 2*WV8; }
    else if (gid < XV8 + 4*WV8)    { src = W3; dst = W3b; off = gid - XV8 - 3*WV8; }
    else return;
    off *= 8;
    float4 a = *(const float4*)(src + off);
    float4 b = *(const float4*)(src + off + 4);
    s8v o;
    o[0] = f2bf(a.x); o[1] = f2bf(a.y); o[2] = f2bf(a.z); o[3] = f2bf(a.w);
    o[4] = f2bf(b.x); o[5] = f2bf(b.y); o[6] = f2bf(b.z); o[7] = f2bf(b.w);
    *(s8v*)(dst + off) = o;
}

// ---------------------------------------------------------------------------
// MFMA GEMM, 128x128 tile, BK=32, 4 waves (2x2, 64x64 each).
// EPI 0: fused QKV. seg 0/1 -> bf16 [B,NH,S,HD] (Q scaled by 0.125*log2e);
//        seg 2 (V) -> bf16 V^T [B,NH,HD,S] with k-PERMUTED columns (kperm).
// EPI 1: out-proj -> fp32 [4096,768] + bias + residual.
// ---------------------------------------------------------------------------
template<int EPI>
__global__ __launch_bounds__(256)
void gemm_mfma(const short* __restrict__ A,
               const short* __restrict__ Wq, const short* __restrict__ Wk,
               const short* __restrict__ Wv,
               const float* __restrict__ bq, const float* __restrict__ bk,
               const float* __restrict__ bv,
               short* __restrict__ Qo, short* __restrict__ Ko, short* __restrict__ Vo,
               const float* __restrict__ Xres, float* __restrict__ Fo)
{
    __shared__ __align__(16) short As[128*32];
    __shared__ __align__(16) short Bs[128*32];

    const int tid  = threadIdx.x;
    const int w    = tid >> 6;
    const int lane = tid & 63;
    const int g    = lane >> 4;
    const int r    = lane & 15;
    const int wr   = w >> 1;
    const int wc   = w & 1;
    const int m0   = blockIdx.y * 128;

    int n0;
    int seg = 0;
    const short* Wb; const float* bias; short* outp; float scale;
    if (EPI == 0) {
        seg = blockIdx.x / 6;
        n0 = (blockIdx.x % 6) * 128;
        Wb   = seg == 0 ? Wq : seg == 1 ? Wk : Wv;
        bias = seg == 0 ? bq : seg == 1 ? bk : bv;
        outp = seg == 0 ? Qo : seg == 1 ? Ko : Vo;
        scale = seg == 0 ? (0.125f * L2E) : 1.0f;
    } else {
        n0 = blockIdx.x * 128;
        Wb = Wq; bias = bq; outp = nullptr; scale = 1.0f;
    }

    const int lrow = lane >> 2;
    const int lcol = (lane & 3) * 8;
    const short* Ag0 = A  + (size_t)(m0 + w*32 + lrow) * HH + lcol;
    const short* Bg0 = Wb + (size_t)(n0 + w*32 + lrow) * HH + lcol;
    short* Al0 = As + (w*32)      * 32;
    short* Al1 = As + (w*32 + 16) * 32;
    short* Bl0 = Bs + (w*32)      * 32;
    short* Bl1 = Bs + (w*32 + 16) * 32;

    f4v acc[4][4];
    #pragma unroll
    for (int i = 0; i < 4; i++)
        #pragma unroll
        for (int j = 0; j < 4; j++) acc[i][j] = (f4v){0.f,0.f,0.f,0.f};

    for (int kt = 0; kt < HH/32; ++kt) {
        const int k0 = kt * 32;
        gld16(Ag0 + k0,           Al0);
        gld16(Ag0 + k0 + 16*HH,   Al1);
        gld16(Bg0 + k0,           Bl0);
        gld16(Bg0 + k0 + 16*HH,   Bl1);
        __syncthreads();

        s8v af[4], bf[4];
        #pragma unroll
        for (int mi = 0; mi < 4; mi++)
            af[mi] = *(const s8v*)(As + (wr*64 + mi*16 + r)*32 + g*8);
        #pragma unroll
        for (int ni = 0; ni < 4; ni++)
            bf[ni] = *(const s8v*)(Bs + (wc*64 + ni*16 + r)*32 + g*8);
        __builtin_amdgcn_s_setprio(1);
        #pragma unroll
        for (int mi = 0; mi < 4; mi++)
            #pragma unroll
            for (int ni = 0; ni < 4; ni++)
                acc[mi][ni] = __builtin_amdgcn_mfma_f32_16x16x32_bf16(af[mi], bf[ni], acc[mi][ni], 0, 0, 0);
        __builtin_amdgcn_s_setprio(0);
        __syncthreads();
    }

    if (EPI == 0) {
        if (seg < 2) {
            #pragma unroll
            for (int mi = 0; mi < 4; mi++) {
                #pragma unroll
                for (int j = 0; j < 4; j++) {
                    const int m = m0 + wr*64 + mi*16 + 4*g + j;
                    const int bb = m >> 11;
                    const int s  = m & 2047;
                    #pragma unroll
                    for (int ni = 0; ni < 4; ni++) {
                        const int n = n0 + wc*64 + ni*16 + r;
                        const int h = n >> 6;
                        const int d = n & 63;
                        outp[((size_t)((bb*NHEADS + h)*SEQ) + s)*HDIM + d] =
                            f2bf((acc[mi][ni][j] + bias[n]) * scale);
                    }
                }
            }
        } else {
            // V^T direct, k-permuted columns: 4 contiguous s stay contiguous
            #pragma unroll
            for (int mi = 0; mi < 4; mi++) {
                const int m  = m0 + wr*64 + mi*16 + 4*g;   // 4-aligned
                const int bb = m >> 11;
                const int s  = m & 2047;
                const int sp = kperm(s);                   // 4-aligned too
                #pragma unroll
                for (int ni = 0; ni < 4; ni++) {
                    const int n = n0 + wc*64 + ni*16 + r;
                    const int h = n >> 6;
                    const int d = n & 63;
                    s4v pk;
                    #pragma unroll
                    for (int j = 0; j < 4; j++)
                        pk[j] = f2bf(acc[mi][ni][j] + bias[n]);
                    *(s4v*)(outp + ((size_t)((bb*NHEADS + h)*HDIM) + d)*SEQ + sp) = pk;
                }
            }
        }
    } else {
        #pragma unroll
        for (int mi = 0; mi < 4; mi++) {
            #pragma unroll
            for (int j = 0; j < 4; j++) {
                const int m = m0 + wr*64 + mi*16 + 4*g + j;
                #pragma unroll
                for (int ni = 0; ni < 4; ni++) {
                    const int n = n0 + wc*64 + ni*16 + r;
                    Fo[(size_t)m*HH + n] = acc[mi][ni][j] + bias[n] + Xres[(size_t)m*HH + n];
                }
            }
        }
    }
}

// ---------------------------------------------------------------------------
// Flash attention, bf16 MFMA, 8 waves / 512 threads, KV-parity split.
// SWAPPED QK^T: mfma(kf, qf) -> lane (r,g) holds P[k=4g+i+16jt][q=r].
// With k-slot permutation pos=8g+4jt+i (matched by V^T's kperm layout and
// the permuted mask LDS), the PV A-fragment is built ENTIRELY in-register
// (4 cvt_pk, no P LDS, no shuffles). ds ops/pair/wave: 4 kf + 1 mask + 4 vf.
// Fixed-max exp2 softmax; scalar per-lane l partial; merge at end.
// LDS 36 KB (K 2x8K, V 2x8K, mask 4K) -> conflict-free 128B-row swizzles.
// ---------------------------------------------------------------------------
#define NPAIR (SEQ/64)
__global__ __launch_bounds__(512, 4)
void attn_mfma(const short* __restrict__ Q, const short* __restrict__ K,
               const short* __restrict__ VT, const float* __restrict__ mask,
               short* __restrict__ CTX)
{
    // XCD swizzle: 768 blocks = 8 XCDs x 96
    const int wgid = (blockIdx.x & 7) * 96 + (blockIdx.x >> 3);
    const int qt = wgid & 31;
    const int bh = wgid >> 5;
    const int h  = bh % NHEADS;
    const int b  = bh / NHEADS;

    const size_t hb = (size_t)(b * NHEADS + h);
    const short* Qg  = Q  + hb * SEQ * HDIM;
    const short* Kg  = K  + hb * SEQ * HDIM;
    const short* VTg = VT + hb * HDIM * SEQ;   // k-permuted columns

    __shared__ __align__(16) char lds[36864];
    char* Kbase = lds;                    // [2 db][64 k-rows][128B]
    char* Vbase = lds + 16384;            // [2 db][64 d-rows][128B], k-pos order
    short* Mper = (short*)(lds + 32768);  // [2048] bf16 madd, k-pos order

    const int tid  = threadIdx.x;
    const int w    = tid >> 6;
    const int grp  = w >> 2;
    const int wq   = w & 3;
    const int lane = tid & 63;
    const int g    = lane >> 4;
    const int r    = lane & 15;
    const int q0   = qt * 64;

    const short* qrow = Qg + (size_t)(q0 + wq*16 + r) * HDIM;
    const s8v qf0 = *(const s8v*)(qrow + 8*g);
    const s8v qf1 = *(const s8v*)(qrow + 8*g + 32);

    // one-time mask -> permuted bf16 LDS (512 threads x 4 entries)
    {
        float4 mv = *(const float4*)(mask + b*SEQ + tid*4);
        s4v md;
        md[0] = f2bf((mv.x - 1.0f) * (10000.0f * L2E));
        md[1] = f2bf((mv.y - 1.0f) * (10000.0f * L2E));
        md[2] = f2bf((mv.z - 1.0f) * (10000.0f * L2E));
        md[3] = f2bf((mv.w - 1.0f) * (10000.0f * L2E));
        *(s4v*)(Mper + kperm(tid*4)) = md;
    }

    f4v acc[4];
    #pragma unroll
    for (int t = 0; t < 4; t++) acc[t] = (f4v){0.f, 0.f, 0.f, 0.f};
    float lpart = 0.0f;

    const int srow = lane >> 3;
    const int scol = 8 * ((lane & 7) ^ srow);

    #define STAGE(PT, DB) do {                                                 \
        const int pk0 = (PT) * 64;                                             \
        char* kd = Kbase + (DB)*8192 + w*1024;                                 \
        gld16(Kg + (size_t)(pk0 + 8*w + srow)*HDIM + scol, kd);                \
        char* vd = Vbase + (DB)*8192 + w*1024;                                 \
        gld16(VTg + (size_t)(8*w + srow)*SEQ + pk0 + scol, vd);                \
    } while (0)

    STAGE(0, 0);
    __syncthreads();   // staging + mask preload

    for (int pt = 0; pt < NPAIR; ++pt) {
        const int db = pt & 1;
        if (pt + 1 < NPAIR) STAGE(pt + 1, db ^ 1);   // async, drained at barrier

        const char* Kc = Kbase + db*8192 + grp*4096; // 32 k-rows x 128B
        const char* Vc = Vbase + db*8192;            // 64 d-rows x 128B

        // madd: 8 bf16 at positions (pt*64+grp*32) + 8g..+7 (broadcast read)
        s8v mraw = *(const s8v*)(Mper + pt*64 + grp*32 + 8*g);

        // ---- swapped QK^T: p[jt][i] = S[k=4g+i+16jt][q=wq*16+r] + madd ----
        f4v p0, p1;
        __builtin_amdgcn_s_setprio(1);
        {
            const int sw = (r & 7) << 4;
            const char* kb0 = Kc + r * 128;          // jt=0 rows
            const char* kb1 = Kc + (16 + r) * 128;   // jt=1 rows
            s8v ka0 = *(const s8v*)(kb0 + ((16*g)      ^ sw));
            s8v ka1 = *(const s8v*)(kb0 + ((16*g + 64) ^ sw));
            s8v kb0f = *(const s8v*)(kb1 + ((16*g)      ^ sw));
            s8v kb1f = *(const s8v*)(kb1 + ((16*g + 64) ^ sw));
            f4v z0 = (f4v){0.f, 0.f, 0.f, 0.f};
            z0 = __builtin_amdgcn_mfma_f32_16x16x32_bf16(ka0, qf0, z0, 0, 0, 0);
            z0 = __builtin_amdgcn_mfma_f32_16x16x32_bf16(ka1, qf1, z0, 0, 0, 0);
            f4v z1 = (f4v){0.f, 0.f, 0.f, 0.f};
            z1 = __builtin_amdgcn_mfma_f32_16x16x32_bf16(kb0f, qf0, z1, 0, 0, 0);
            z1 = __builtin_amdgcn_mfma_f32_16x16x32_bf16(kb1f, qf1, z1, 0, 0, 0);
            p0 = z0; p1 = z1;
        }
        __builtin_amdgcn_s_setprio(0);

        #pragma unroll
        for (int i = 0; i < 4; i++) {
            union { unsigned u; float f; } m0c, m1c;
            m0c.u = ((unsigned)(unsigned short)mraw[i])     << 16;  // slot 4*0+i
            m1c.u = ((unsigned)(unsigned short)mraw[4 + i]) << 16;  // slot 4*1+i
            p0[i] = EXP2(p0[i] + m0c.f);
            p1[i] = EXP2(p1[i] + m1c.f);
        }
        lpart += ((p0[0] + p0[1]) + (p0[2] + p0[3]))
               + ((p1[0] + p1[1]) + (p1[2] + p1[3]));

        // ---- PV A-fragment fully in-register (slot z = p[z>>2][z&3]) ----
        union { unsigned u[4]; s8v v; } pfu;
        pfu.u[0] = cvt_pk_bf16(p0[0], p0[1]);
        pfu.u[1] = cvt_pk_bf16(p0[2], p0[3]);
        pfu.u[2] = cvt_pk_bf16(p1[0], p1[1]);
        pfu.u[3] = cvt_pk_bf16(p1[2], p1[3]);
        const s8v pf = pfu.v;

        // ---- ctx += P @ V (k-extent 32, permuted positions grp*32+8g..) ----
        __builtin_amdgcn_s_setprio(1);
        #pragma unroll
        for (int t4 = 0; t4 < 4; t4++) {
            const int vrow = 16*t4 + r;
            s8v vf = *(const s8v*)(Vc + vrow*128 + ((16*(4*grp + g)) ^ ((r & 7) << 4)));
            acc[t4] = __builtin_amdgcn_mfma_f32_16x16x32_bf16(pf, vf, acc[t4], 0, 0, 0);
        }
        __builtin_amdgcn_s_setprio(0);

        __syncthreads();   // drains prefetch vmcnt; next pair ready, bufs free
    }

    // ---- reduce l across g-lanes (k-slices of this grp) ----
    lpart += __shfl_xor(lpart, 16);
    lpart += __shfl_xor(lpart, 32);   // all lanes with same r: l for q=wq*16+r

    // ---- merge parity partials (fixed-max => plain adds) ----
    float* lbuf = (float*)(lds + 20480);
    if (grp == 1) {
        float* mb = (float*)(lds + wq*5120 + lane*80);
        *(f4v*)(mb)      = acc[0];
        *(f4v*)(mb + 4)  = acc[1];
        *(f4v*)(mb + 8)  = acc[2];
        *(f4v*)(mb + 12) = acc[3];
        lbuf[wq*64 + lane] = lpart;
    }
    __syncthreads();
    if (grp == 0) {
        const float* mb = (const float*)(lds + wq*5120 + lane*80);
        acc[0] += *(const f4v*)(mb);
        acc[1] += *(const f4v*)(mb + 4);
        acc[2] += *(const f4v*)(mb + 8);
        acc[3] += *(const f4v*)(mb + 12);
        lpart  += lbuf[wq*64 + lane];

        #pragma unroll
        for (int i = 0; i < 4; i++) {
            const float invl = 1.0f / __shfl(lpart, 4*g + i);
            const size_t rowbase = ((size_t)(b*SEQ) + q0 + wq*16 + 4*g + i) * HH + h*HDIM;
            #pragma unroll
            for (int t4 = 0; t4 < 4; t4++)
                CTX[rowbase + 16*t4 + r] = f2bf(acc[t4][i] * invl);
        }
    }
    #undef STAGE
}

// ---------------------------------------------------------------------------
// In-place LayerNorm over rows of 768.
// ---------------------------------------------------------------------------
__global__ __launch_bounds__(256)
void ln_kernel(float* __restrict__ y, const float* __restrict__ gamma,
               const float* __restrict__ beta)
{
    const int row = blockIdx.x;
    float* p = y + (size_t)row * HH;
    const int tid = threadIdx.x;

    float v[3];
    float s = 0.f, ss = 0.f;
    #pragma unroll
    for (int i = 0; i < 3; i++) {
        float x = p[tid + i*256];
        v[i] = x;
        s += x;
        ss += x * x;
    }
    #pragma unroll
    for (int off = 32; off > 0; off >>= 1) {
        s  += __shfl_down(s,  off);
        ss += __shfl_down(ss, off);
    }
    __shared__ float sbuf[4], ssbuf[4];
    __shared__ float mu_s, rstd_s;
    const int wave = tid >> 6;
    if ((tid & 63) == 0) { sbuf[wave] = s; ssbuf[wave] = ss; }
    __syncthreads();
    if (tid == 0) {
        float S  = sbuf[0] + sbuf[1] + sbuf[2] + sbuf[3];
        float SS = ssbuf[0] + ssbuf[1] + ssbuf[2] + ssbuf[3];
        float mu = S * (1.0f / HH);
        float var = SS * (1.0f / HH) - mu * mu;
        mu_s = mu;
        rstd_s = rsqrtf(var + 1e-5f);
    }
    __syncthreads();
    const float mu = mu_s, rstd = rstd_s;
    #pragma unroll
    for (int i = 0; i < 3; i++) {
        const int c = tid + i*256;
        p[c] = (v[i] - mu) * rstd * gamma[c] + beta[c];
    }
}

// ---------------------------------------------------------------------------
extern "C" void kernel_launch(void* const* d_in, const int* in_sizes, int n_in,
                              void* d_out, int out_size, void* d_ws, size_t ws_size,
                              hipStream_t stream)
{
    const float* x     = (const float*)d_in[0];
    const float* mask  = (const float*)d_in[1];
    const float* Wq    = (const float*)d_in[2];
    const float* bq    = (const float*)d_in[3];
    const float* Wk    = (const float*)d_in[4];
    const float* bk    = (const float*)d_in[5];
    const float* Wv    = (const float*)d_in[6];
    const float* bv    = (const float*)d_in[7];
    const float* Wo    = (const float*)d_in[8];
    const float* bo    = (const float*)d_in[9];
    const float* gamma = (const float*)d_in[10];
    const float* beta  = (const float*)d_in[11];

    const size_t PER = (size_t)NB * NHEADS * SEQ * HDIM;
    const size_t WSZ = (size_t)HH * HH;
    short* wsS  = (short*)d_ws;
    short* Xb   = wsS;          // dead after QKV GEMM -> reused as CTXb
    short* Wqb  = wsS + PER;
    short* Wkb  = Wqb + WSZ;
    short* Wvb  = Wkb + WSZ;
    short* Wob  = Wvb + WSZ;
    short* Qb   = Wob + WSZ;
    short* Kb   = Qb + PER;
    short* VTb  = Kb + PER;     // k-permuted V^T written directly by the GEMM
    short* CTXb = Xb;
    float* out  = (float*)d_out;

    cvt_kernel<<<2688, 256, 0, stream>>>(x, Xb, Wq, Wqb, Wk, Wkb, Wv, Wvb, Wo, Wob);

    gemm_mfma<0><<<dim3(18, 32), 256, 0, stream>>>(
        Xb, Wqb, Wkb, Wvb, bq, bk, bv, Qb, Kb, VTb, nullptr, nullptr);

    attn_mfma<<<768, 512, 0, stream>>>(Qb, Kb, VTb, mask, CTXb);

    gemm_mfma<1><<<dim3(6, 32), 256, 0, stream>>>(
        CTXb, Wob, nullptr, nullptr, bo, nullptr, nullptr,
        nullptr, nullptr, nullptr, x, out);

    ln_kernel<<<NB*SEQ, 256, 0, stream>>>(out, gamma, beta);
}

// Round 11
// 108.422 us; speedup vs baseline: 1.7011x; 1.0277x over previous
//
#include <hip/hip_runtime.h>
#include <math.h>

#define HH 768
#define NHEADS 12
#define HDIM 64
#define SEQ 2048
#define NB 2
#define L2E 1.44269504088896f

typedef __attribute__((ext_vector_type(8))) short s8v;
typedef __attribute__((ext_vector_type(4))) short s4v;
typedef __attribute__((ext_vector_type(4))) float f4v;

static __device__ inline short f2bf(float f) {
    union { float f; unsigned u; } v; v.f = f;
    unsigned r = v.u + 0x7fff + ((v.u >> 16) & 1);   // RNE
    return (short)(r >> 16);
}

#if __has_builtin(__builtin_amdgcn_exp2f)
#define EXP2(x) __builtin_amdgcn_exp2f(x)
#else
#define EXP2(x) __expf((x) * 0.6931471805599453f)
#endif

__device__ __forceinline__ unsigned cvt_pk_bf16(float a, float b) {
    unsigned r;
    asm("v_cvt_pk_bf16_f32 %0, %1, %2" : "=v"(r) : "v"(a), "v"(b));
    return r;
}

__device__ __forceinline__ void gld16(const void* g, void* l) {
    __builtin_amdgcn_global_load_lds(
        (const __attribute__((address_space(1))) void*)g,
        (__attribute__((address_space(3))) void*)l, 16, 0, 0);
}

// k-position permutation within each 32-group (shared by V^T layout, mask
// layout, and the PV MFMA slot order): pos = 8*((k>>2)&3) + 4*((k>>4)&1) + (k&3)
__device__ __forceinline__ int kperm(int k) {
    return (k & ~31) | (((k >> 2) & 3) << 3) | (((k >> 4) & 1) << 2) | (k & 3);
}

// ---------------------------------------------------------------------------
// fp32 -> bf16 conversion: X (4096x768) and the 4 weight matrices (768x768).
// ---------------------------------------------------------------------------
#define XV8   393216
#define WV8   73728
__global__ __launch_bounds__(256)
void cvt_kernel(const float* __restrict__ X, short* __restrict__ Xb,
                const float* __restrict__ W0, short* __restrict__ W0b,
                const float* __restrict__ W1, short* __restrict__ W1b,
                const float* __restrict__ W2, short* __restrict__ W2b,
                const float* __restrict__ W3, short* __restrict__ W3b)
{
    int gid = blockIdx.x * 256 + threadIdx.x;
    const float* src; short* dst; size_t off;
    if      (gid < XV8)            { src = X;  dst = Xb;  off = gid; }
    else if (gid < XV8 + WV8)      { src = W0; dst = W0b; off = gid - XV8; }
    else if (gid < XV8 + 2*WV8)    { src = W1; dst = W1b; off = gid - XV8 - WV8; }
    else if (gid < XV8 + 3*WV8)    { src = W2; dst = W2b; off = gid - XV8 - 2*WV8; }
    else if (gid < XV8 + 4*WV8)    { src = W3; dst = W3b; off = gid - XV8 - 3*WV8; }
    else return;
    off *= 8;
    float4 a = *(const float4*)(src + off);
    float4 b = *(const float4*)(src + off + 4);
    s8v o;
    o[0] = f2bf(a.x); o[1] = f2bf(a.y); o[2] = f2bf(a.z); o[3] = f2bf(a.w);
    o[4] = f2bf(b.x); o[5] = f2bf(b.y); o[6] = f2bf(b.z); o[7] = f2bf(b.w);
    *(s8v*)(dst + off) = o;
}

// ---------------------------------------------------------------------------
// MFMA GEMM, 128x128 tile, BK=32, 4 waves (2x2, 64x64 each).
// EPI 0: fused QKV. seg 0/1 -> bf16 [B,NH,S,HD] (Q scaled by 0.125*log2e);
//        seg 2 (V) -> bf16 V^T [B,NH,HD,S] with k-PERMUTED columns (kperm).
// EPI 1: out-proj -> fp32 [4096,768] + bias + residual.
// ---------------------------------------------------------------------------
template<int EPI>
__global__ __launch_bounds__(256)
void gemm_mfma(const short* __restrict__ A,
               const short* __restrict__ Wq, const short* __restrict__ Wk,
               const short* __restrict__ Wv,
               const float* __restrict__ bq, const float* __restrict__ bk,
               const float* __restrict__ bv,
               short* __restrict__ Qo, short* __restrict__ Ko, short* __restrict__ Vo,
               const float* __restrict__ Xres, float* __restrict__ Fo)
{
    __shared__ __align__(16) short As[128*32];
    __shared__ __align__(16) short Bs[128*32];

    const int tid  = threadIdx.x;
    const int w    = tid >> 6;
    const int lane = tid & 63;
    const int g    = lane >> 4;
    const int r    = lane & 15;
    const int wr   = w >> 1;
    const int wc   = w & 1;
    const int m0   = blockIdx.y * 128;

    int n0;
    int seg = 0;
    const short* Wb; const float* bias; short* outp; float scale;
    if (EPI == 0) {
        seg = blockIdx.x / 6;
        n0 = (blockIdx.x % 6) * 128;
        Wb   = seg == 0 ? Wq : seg == 1 ? Wk : Wv;
        bias = seg == 0 ? bq : seg == 1 ? bk : bv;
        outp = seg == 0 ? Qo : seg == 1 ? Ko : Vo;
        scale = seg == 0 ? (0.125f * L2E) : 1.0f;
    } else {
        n0 = blockIdx.x * 128;
        Wb = Wq; bias = bq; outp = nullptr; scale = 1.0f;
    }

    const int lrow = lane >> 2;
    const int lcol = (lane & 3) * 8;
    const short* Ag0 = A  + (size_t)(m0 + w*32 + lrow) * HH + lcol;
    const short* Bg0 = Wb + (size_t)(n0 + w*32 + lrow) * HH + lcol;
    short* Al0 = As + (w*32)      * 32;
    short* Al1 = As + (w*32 + 16) * 32;
    short* Bl0 = Bs + (w*32)      * 32;
    short* Bl1 = Bs + (w*32 + 16) * 32;

    f4v acc[4][4];
    #pragma unroll
    for (int i = 0; i < 4; i++)
        #pragma unroll
        for (int j = 0; j < 4; j++) acc[i][j] = (f4v){0.f,0.f,0.f,0.f};

    for (int kt = 0; kt < HH/32; ++kt) {
        const int k0 = kt * 32;
        gld16(Ag0 + k0,           Al0);
        gld16(Ag0 + k0 + 16*HH,   Al1);
        gld16(Bg0 + k0,           Bl0);
        gld16(Bg0 + k0 + 16*HH,   Bl1);
        __syncthreads();

        s8v af[4], bf[4];
        #pragma unroll
        for (int mi = 0; mi < 4; mi++)
            af[mi] = *(const s8v*)(As + (wr*64 + mi*16 + r)*32 + g*8);
        #pragma unroll
        for (int ni = 0; ni < 4; ni++)
            bf[ni] = *(const s8v*)(Bs + (wc*64 + ni*16 + r)*32 + g*8);
        __builtin_amdgcn_s_setprio(1);
        #pragma unroll
        for (int mi = 0; mi < 4; mi++)
            #pragma unroll
            for (int ni = 0; ni < 4; ni++)
                acc[mi][ni] = __builtin_amdgcn_mfma_f32_16x16x32_bf16(af[mi], bf[ni], acc[mi][ni], 0, 0, 0);
        __builtin_amdgcn_s_setprio(0);
        __syncthreads();
    }

    if (EPI == 0) {
        if (seg < 2) {
            #pragma unroll
            for (int mi = 0; mi < 4; mi++) {
                #pragma unroll
                for (int j = 0; j < 4; j++) {
                    const int m = m0 + wr*64 + mi*16 + 4*g + j;
                    const int bb = m >> 11;
                    const int s  = m & 2047;
                    #pragma unroll
                    for (int ni = 0; ni < 4; ni++) {
                        const int n = n0 + wc*64 + ni*16 + r;
                        const int h = n >> 6;
                        const int d = n & 63;
                        outp[((size_t)((bb*NHEADS + h)*SEQ) + s)*HDIM + d] =
                            f2bf((acc[mi][ni][j] + bias[n]) * scale);
                    }
                }
            }
        } else {
            // V^T direct, k-permuted columns: 4 contiguous s stay contiguous
            #pragma unroll
            for (int mi = 0; mi < 4; mi++) {
                const int m  = m0 + wr*64 + mi*16 + 4*g;   // 4-aligned
                const int bb = m >> 11;
                const int s  = m & 2047;
                const int sp = kperm(s);                   // 4-aligned too
                #pragma unroll
                for (int ni = 0; ni < 4; ni++) {
                    const int n = n0 + wc*64 + ni*16 + r;
                    const int h = n >> 6;
                    const int d = n & 63;
                    s4v pk;
                    #pragma unroll
                    for (int j = 0; j < 4; j++)
                        pk[j] = f2bf(acc[mi][ni][j] + bias[n]);
                    *(s4v*)(outp + ((size_t)((bb*NHEADS + h)*HDIM) + d)*SEQ + sp) = pk;
                }
            }
        }
    } else {
        #pragma unroll
        for (int mi = 0; mi < 4; mi++) {
            #pragma unroll
            for (int j = 0; j < 4; j++) {
                const int m = m0 + wr*64 + mi*16 + 4*g + j;
                #pragma unroll
                for (int ni = 0; ni < 4; ni++) {
                    const int n = n0 + wc*64 + ni*16 + r;
                    Fo[(size_t)m*HH + n] = acc[mi][ni][j] + bias[n] + Xres[(size_t)m*HH + n];
                }
            }
        }
    }
}

// ---------------------------------------------------------------------------
// Flash attention, bf16 MFMA, 8 waves / 512 threads, KV-parity split.
// SWAPPED QK^T: mfma(kf, qf) -> lane (r,g) holds P[k][q=r]; k-slot
// permutation matched by V^T kperm layout and permuted fp32 mask LDS.
// Mask applied as MFMA C-INIT (two broadcast ds_read_b128 per pair,
// zero VALU). PV A-fragment built in-register via 4 cvt_pk.
// Fixed-max exp2 softmax; scalar per-lane l; parity merge at end.
// LDS 40 KB (K 2x8K, V 2x8K, mask-f32 8K); 128B rows, conflict-free.
// ---------------------------------------------------------------------------
#define NPAIR (SEQ/64)
__global__ __launch_bounds__(512, 4)
void attn_mfma(const short* __restrict__ Q, const short* __restrict__ K,
               const short* __restrict__ VT, const float* __restrict__ mask,
               short* __restrict__ CTX)
{
    // XCD swizzle: 768 blocks = 8 XCDs x 96
    const int wgid = (blockIdx.x & 7) * 96 + (blockIdx.x >> 3);
    const int qt = wgid & 31;
    const int bh = wgid >> 5;
    const int h  = bh % NHEADS;
    const int b  = bh / NHEADS;

    const size_t hb = (size_t)(b * NHEADS + h);
    const short* Qg  = Q  + hb * SEQ * HDIM;
    const short* Kg  = K  + hb * SEQ * HDIM;
    const short* VTg = VT + hb * HDIM * SEQ;   // k-permuted columns

    __shared__ __align__(16) char lds[40960];
    char* Kbase = lds;                    // [2 db][64 k-rows][128B]
    char* Vbase = lds + 16384;            // [2 db][64 d-rows][128B], k-pos order
    float* Mf   = (float*)(lds + 32768);  // [2048] fp32 madd, k-pos order

    const int tid  = threadIdx.x;
    const int w    = tid >> 6;
    const int grp  = w >> 2;
    const int wq   = w & 3;
    const int lane = tid & 63;
    const int g    = lane >> 4;
    const int r    = lane & 15;
    const int q0   = qt * 64;

    const short* qrow = Qg + (size_t)(q0 + wq*16 + r) * HDIM;
    const s8v qf0 = *(const s8v*)(qrow + 8*g);
    const s8v qf1 = *(const s8v*)(qrow + 8*g + 32);

    // one-time mask -> permuted fp32 LDS (512 threads x 4 entries)
    {
        float4 mv = *(const float4*)(mask + b*SEQ + tid*4);
        f4v md;
        md[0] = (mv.x - 1.0f) * (10000.0f * L2E);
        md[1] = (mv.y - 1.0f) * (10000.0f * L2E);
        md[2] = (mv.z - 1.0f) * (10000.0f * L2E);
        md[3] = (mv.w - 1.0f) * (10000.0f * L2E);
        *(f4v*)(Mf + kperm(tid*4)) = md;
    }

    f4v acc[4];
    #pragma unroll
    for (int t = 0; t < 4; t++) acc[t] = (f4v){0.f, 0.f, 0.f, 0.f};
    float lpart = 0.0f;

    const int srow = lane >> 3;
    const int scol = 8 * ((lane & 7) ^ srow);

    #define STAGE(PT, DB) do {                                                 \
        const int pk0 = (PT) * 64;                                             \
        char* kd = Kbase + (DB)*8192 + w*1024;                                 \
        gld16(Kg + (size_t)(pk0 + 8*w + srow)*HDIM + scol, kd);                \
        char* vd = Vbase + (DB)*8192 + w*1024;                                 \
        gld16(VTg + (size_t)(8*w + srow)*SEQ + pk0 + scol, vd);                \
    } while (0)

    STAGE(0, 0);
    __syncthreads();   // staging + mask preload

    for (int pt = 0; pt < NPAIR; ++pt) {
        const int db = pt & 1;
        if (pt + 1 < NPAIR) STAGE(pt + 1, db ^ 1);   // async, drained at barrier

        const char* Kc = Kbase + db*8192 + grp*4096; // 32 k-rows x 128B
        const char* Vc = Vbase + db*8192;            // 64 d-rows x 128B

        // madd C-init: slots (pt*64+grp*32+8g) + 0..3 (z0), +4..7 (z1)
        const float* mrow = Mf + pt*64 + grp*32 + 8*g;
        f4v z0 = *(const f4v*)(mrow);
        f4v z1 = *(const f4v*)(mrow + 4);

        // ---- swapped QK^T: z[jt][i] = S[k] + madd[k], k=4g+i+16jt ----
        __builtin_amdgcn_s_setprio(1);
        {
            const int sw = (r & 7) << 4;
            const char* kb0 = Kc + r * 128;          // jt=0 rows
            const char* kb1 = Kc + (16 + r) * 128;   // jt=1 rows
            s8v ka0 = *(const s8v*)(kb0 + ((16*g)      ^ sw));
            s8v ka1 = *(const s8v*)(kb0 + ((16*g + 64) ^ sw));
            s8v kc0 = *(const s8v*)(kb1 + ((16*g)      ^ sw));
            s8v kc1 = *(const s8v*)(kb1 + ((16*g + 64) ^ sw));
            z0 = __builtin_amdgcn_mfma_f32_16x16x32_bf16(ka0, qf0, z0, 0, 0, 0);
            z0 = __builtin_amdgcn_mfma_f32_16x16x32_bf16(ka1, qf1, z0, 0, 0, 0);
            z1 = __builtin_amdgcn_mfma_f32_16x16x32_bf16(kc0, qf0, z1, 0, 0, 0);
            z1 = __builtin_amdgcn_mfma_f32_16x16x32_bf16(kc1, qf1, z1, 0, 0, 0);
        }
        __builtin_amdgcn_s_setprio(0);

        #pragma unroll
        for (int i = 0; i < 4; i++) {
            z0[i] = EXP2(z0[i]);
            z1[i] = EXP2(z1[i]);
        }
        lpart += ((z0[0] + z0[1]) + (z0[2] + z0[3]))
               + ((z1[0] + z1[1]) + (z1[2] + z1[3]));

        // ---- PV A-fragment fully in-register (slot z = p[z>>2][z&3]) ----
        union { unsigned u[4]; s8v v; } pfu;
        pfu.u[0] = cvt_pk_bf16(z0[0], z0[1]);
        pfu.u[1] = cvt_pk_bf16(z0[2], z0[3]);
        pfu.u[2] = cvt_pk_bf16(z1[0], z1[1]);
        pfu.u[3] = cvt_pk_bf16(z1[2], z1[3]);
        const s8v pf = pfu.v;

        // ---- ctx += P @ V (k-extent 32, permuted positions grp*32+8g..) ----
        __builtin_amdgcn_s_setprio(1);
        #pragma unroll
        for (int t4 = 0; t4 < 4; t4++) {
            const int vrow = 16*t4 + r;
            s8v vf = *(const s8v*)(Vc + vrow*128 + ((16*(4*grp + g)) ^ ((r & 7) << 4)));
            acc[t4] = __builtin_amdgcn_mfma_f32_16x16x32_bf16(pf, vf, acc[t4], 0, 0, 0);
        }
        __builtin_amdgcn_s_setprio(0);

        __syncthreads();   // drains prefetch vmcnt; next pair ready, bufs free
    }

    // ---- reduce l across g-lanes (k-slices of this grp) ----
    lpart += __shfl_xor(lpart, 16);
    lpart += __shfl_xor(lpart, 32);   // all lanes with same r: l for q=wq*16+r

    // ---- merge parity partials (fixed-max => plain adds) ----
    float* lbuf = (float*)(lds + 20480);
    if (grp == 1) {
        float* mb = (float*)(lds + wq*5120 + lane*80);
        *(f4v*)(mb)      = acc[0];
        *(f4v*)(mb + 4)  = acc[1];
        *(f4v*)(mb + 8)  = acc[2];
        *(f4v*)(mb + 12) = acc[3];
        lbuf[wq*64 + lane] = lpart;
    }
    __syncthreads();
    if (grp == 0) {
        const float* mb = (const float*)(lds + wq*5120 + lane*80);
        acc[0] += *(const f4v*)(mb);
        acc[1] += *(const f4v*)(mb + 4);
        acc[2] += *(const f4v*)(mb + 8);
        acc[3] += *(const f4v*)(mb + 12);
        lpart  += lbuf[wq*64 + lane];

        #pragma unroll
        for (int i = 0; i < 4; i++) {
            const float invl = 1.0f / __shfl(lpart, 4*g + i);
            const size_t rowbase = ((size_t)(b*SEQ) + q0 + wq*16 + 4*g + i) * HH + h*HDIM;
            #pragma unroll
            for (int t4 = 0; t4 < 4; t4++)
                CTX[rowbase + 16*t4 + r] = f2bf(acc[t4][i] * invl);
        }
    }
    #undef STAGE
}

// ---------------------------------------------------------------------------
// In-place LayerNorm over rows of 768.
// ---------------------------------------------------------------------------
__global__ __launch_bounds__(256)
void ln_kernel(float* __restrict__ y, const float* __restrict__ gamma,
               const float* __restrict__ beta)
{
    const int row = blockIdx.x;
    float* p = y + (size_t)row * HH;
    const int tid = threadIdx.x;

    float v[3];
    float s = 0.f, ss = 0.f;
    #pragma unroll
    for (int i = 0; i < 3; i++) {
        float x = p[tid + i*256];
        v[i] = x;
        s += x;
        ss += x * x;
    }
    #pragma unroll
    for (int off = 32; off > 0; off >>= 1) {
        s  += __shfl_down(s,  off);
        ss += __shfl_down(ss, off);
    }
    __shared__ float sbuf[4], ssbuf[4];
    __shared__ float mu_s, rstd_s;
    const int wave = tid >> 6;
    if ((tid & 63) == 0) { sbuf[wave] = s; ssbuf[wave] = ss; }
    __syncthreads();
    if (tid == 0) {
        float S  = sbuf[0] + sbuf[1] + sbuf[2] + sbuf[3];
        float SS = ssbuf[0] + ssbuf[1] + ssbuf[2] + ssbuf[3];
        float mu = S * (1.0f / HH);
        float var = SS * (1.0f / HH) - mu * mu;
        mu_s = mu;
        rstd_s = rsqrtf(var + 1e-5f);
    }
    __syncthreads();
    const float mu = mu_s, rstd = rstd_s;
    #pragma unroll
    for (int i = 0; i < 3; i++) {
        const int c = tid + i*256;
        p[c] = (v[i] - mu) * rstd * gamma[c] + beta[c];
    }
}

// ---------------------------------------------------------------------------
extern "C" void kernel_launch(void* const* d_in, const int* in_sizes, int n_in,
                              void* d_out, int out_size, void* d_ws, size_t ws_size,
                              hipStream_t stream)
{
    const float* x     = (const float*)d_in[0];
    const float* mask  = (const float*)d_in[1];
    const float* Wq    = (const float*)d_in[2];
    const float* bq    = (const float*)d_in[3];
    const float* Wk    = (const float*)d_in[4];
    const float* bk    = (const float*)d_in[5];
    const float* Wv    = (const float*)d_in[6];
    const float* bv    = (const float*)d_in[7];
    const float* Wo    = (const float*)d_in[8];
    const float* bo    = (const float*)d_in[9];
    const float* gamma = (const float*)d_in[10];
    const float* beta  = (const float*)d_in[11];

    const size_t PER = (size_t)NB * NHEADS * SEQ * HDIM;
    const size_t WSZ = (size_t)HH * HH;
    short* wsS  = (short*)d_ws;
    short* Xb   = wsS;          // dead after QKV GEMM -> reused as CTXb
    short* Wqb  = wsS + PER;
    short* Wkb  = Wqb + WSZ;
    short* Wvb  = Wkb + WSZ;
    short* Wob  = Wvb + WSZ;
    short* Qb   = Wob + WSZ;
    short* Kb   = Qb + PER;
    short* VTb  = Kb + PER;     // k-permuted V^T written directly by the GEMM
    short* CTXb = Xb;
    float* out  = (float*)d_out;

    cvt_kernel<<<2688, 256, 0, stream>>>(x, Xb, Wq, Wqb, Wk, Wkb, Wv, Wvb, Wo, Wob);

    gemm_mfma<0><<<dim3(18, 32), 256, 0, stream>>>(
        Xb, Wqb, Wkb, Wvb, bq, bk, bv, Qb, Kb, VTb, nullptr, nullptr);

    attn_mfma<<<768, 512, 0, stream>>>(Qb, Kb, VTb, mask, CTXb);

    gemm_mfma<1><<<dim3(6, 32), 256, 0, stream>>>(
        CTXb, Wob, nullptr, nullptr, bo, nullptr, nullptr,
        nullptr, nullptr, nullptr, x, out);

    ln_kernel<<<NB*SEQ, 256, 0, stream>>>(out, gamma, beta);
}

// Round 12
// 100.349 us; speedup vs baseline: 1.8380x; 1.0805x over previous
//
#include <hip/hip_runtime.h>
#include <math.h>

#define HH 768
#define NHEADS 12
#define HDIM 64
#define SEQ 2048
#define NB 2
#define L2E 1.44269504088896f

typedef __attribute__((ext_vector_type(8))) short s8v;
typedef __attribute__((ext_vector_type(4))) short s4v;
typedef __attribute__((ext_vector_type(4))) float f4v;

static __device__ inline short f2bf(float f) {
    union { float f; unsigned u; } v; v.f = f;
    unsigned r = v.u + 0x7fff + ((v.u >> 16) & 1);   // RNE
    return (short)(r >> 16);
}

#if __has_builtin(__builtin_amdgcn_exp2f)
#define EXP2(x) __builtin_amdgcn_exp2f(x)
#else
#define EXP2(x) __expf((x) * 0.6931471805599453f)
#endif

__device__ __forceinline__ unsigned cvt_pk_bf16(float a, float b) {
    unsigned r;
    asm("v_cvt_pk_bf16_f32 %0, %1, %2" : "=v"(r) : "v"(a), "v"(b));
    return r;
}

__device__ __forceinline__ void gld16(const void* g, void* l) {
    __builtin_amdgcn_global_load_lds(
        (const __attribute__((address_space(1))) void*)g,
        (__attribute__((address_space(3))) void*)l, 16, 0, 0);
}

// k-position permutation within each 32-group (shared by V^T layout, mask
// layout, and the PV MFMA slot order): pos = 8*((k>>2)&3) + 4*((k>>4)&1) + (k&3)
__device__ __forceinline__ int kperm(int k) {
    return (k & ~31) | (((k >> 2) & 3) << 3) | (((k >> 4) & 1) << 2) | (k & 3);
}

// ---------------------------------------------------------------------------
// fp32 -> bf16 conversion: X (4096x768) and the 4 weight matrices (768x768).
// ---------------------------------------------------------------------------
#define XV8   393216
#define WV8   73728
__global__ __launch_bounds__(256)
void cvt_kernel(const float* __restrict__ X, short* __restrict__ Xb,
                const float* __restrict__ W0, short* __restrict__ W0b,
                const float* __restrict__ W1, short* __restrict__ W1b,
                const float* __restrict__ W2, short* __restrict__ W2b,
                const float* __restrict__ W3, short* __restrict__ W3b)
{
    int gid = blockIdx.x * 256 + threadIdx.x;
    const float* src; short* dst; size_t off;
    if      (gid < XV8)            { src = X;  dst = Xb;  off = gid; }
    else if (gid < XV8 + WV8)      { src = W0; dst = W0b; off = gid - XV8; }
    else if (gid < XV8 + 2*WV8)    { src = W1; dst = W1b; off = gid - XV8 - WV8; }
    else if (gid < XV8 + 3*WV8)    { src = W2; dst = W2b; off = gid - XV8 - 2*WV8; }
    else if (gid < XV8 + 4*WV8)    { src = W3; dst = W3b; off = gid - XV8 - 3*WV8; }
    else return;
    off *= 8;
    float4 a = *(const float4*)(src + off);
    float4 b = *(const float4*)(src + off + 4);
    s8v o;
    o[0] = f2bf(a.x); o[1] = f2bf(a.y); o[2] = f2bf(a.z); o[3] = f2bf(a.w);
    o[4] = f2bf(b.x); o[5] = f2bf(b.y); o[6] = f2bf(b.z); o[7] = f2bf(b.w);
    *(s8v*)(dst + off) = o;
}

// ---------------------------------------------------------------------------
// MFMA GEMM, 64x128 tile, BK=32, 4 waves (2m x 2n, 32x64 each).
// Grid flattened 1D with bijective XCD swizzle.
// EPI 0: fused QKV (1152 blocks). seg 0/1 -> bf16 [B,NH,S,HD] (Q pre-scaled
//        by 0.125*log2e); seg 2 (V) -> bf16 V^T [B,NH,HD,S], kperm columns.
// EPI 1: out-proj (384 blocks) -> fp32 [4096,768] + bias + residual.
// ---------------------------------------------------------------------------
template<int EPI>
__global__ __launch_bounds__(256)
void gemm_mfma(const short* __restrict__ A,
               const short* __restrict__ Wq, const short* __restrict__ Wk,
               const short* __restrict__ Wv,
               const float* __restrict__ bq, const float* __restrict__ bk,
               const float* __restrict__ bv,
               short* __restrict__ Qo, short* __restrict__ Ko, short* __restrict__ Vo,
               const float* __restrict__ Xres, float* __restrict__ Fo)
{
    __shared__ __align__(16) short As[64*32];    // 4 KB
    __shared__ __align__(16) short Bs[128*32];   // 8 KB

    const int tid  = threadIdx.x;
    const int w    = tid >> 6;
    const int lane = tid & 63;
    const int g    = lane >> 4;
    const int r    = lane & 15;
    const int wr   = w >> 1;      // m-half (32 rows)
    const int wc   = w & 1;       // n-half (64 cols)

    // bijective XCD swizzle: NXB = blocks/XCD
    const int NBX = (EPI == 0) ? 18 : 6;
    const int NXB = (EPI == 0) ? 144 : 48;
    const int wg  = (blockIdx.x & 7) * NXB + (blockIdx.x >> 3);
    const int bx  = wg % NBX;
    const int by  = wg / NBX;
    const int m0  = by * 64;

    int n0;
    int seg = 0;
    const short* Wb; const float* bias; short* outp; float scale;
    if (EPI == 0) {
        seg = bx / 6;
        n0 = (bx % 6) * 128;
        Wb   = seg == 0 ? Wq : seg == 1 ? Wk : Wv;
        bias = seg == 0 ? bq : seg == 1 ? bk : bv;
        outp = seg == 0 ? Qo : seg == 1 ? Ko : Vo;
        scale = seg == 0 ? (0.125f * L2E) : 1.0f;
    } else {
        n0 = bx * 128;
        Wb = Wq; bias = bq; outp = nullptr; scale = 1.0f;
    }

    // staging: A = 1 gld16/thread (64 rows x 4 slots); B = 2 gld16/thread
    const int srow = tid >> 2;          // 0..63
    const int scol = (tid & 3) * 8;
    const short* Asrc  = A  + (size_t)(m0 + srow) * HH + scol;
    const short* Bsrc0 = Wb + (size_t)(n0 + srow) * HH + scol;
    const short* Bsrc1 = Wb + (size_t)(n0 + 64 + srow) * HH + scol;
    short* Ald  = As + w*512;           // wave-uniform bases
    short* Bld0 = Bs + w*512;
    short* Bld1 = Bs + 2048 + w*512;

    f4v acc[2][4];
    #pragma unroll
    for (int i = 0; i < 2; i++)
        #pragma unroll
        for (int j = 0; j < 4; j++) acc[i][j] = (f4v){0.f,0.f,0.f,0.f};

    for (int kt = 0; kt < HH/32; ++kt) {
        const int k0 = kt * 32;
        gld16(Asrc  + k0, Ald);
        gld16(Bsrc0 + k0, Bld0);
        gld16(Bsrc1 + k0, Bld1);
        __syncthreads();

        s8v af[2], bf[4];
        #pragma unroll
        for (int mi = 0; mi < 2; mi++)
            af[mi] = *(const s8v*)(As + (wr*32 + mi*16 + r)*32 + g*8);
        #pragma unroll
        for (int ni = 0; ni < 4; ni++)
            bf[ni] = *(const s8v*)(Bs + (wc*64 + ni*16 + r)*32 + g*8);
        __builtin_amdgcn_s_setprio(1);
        #pragma unroll
        for (int mi = 0; mi < 2; mi++)
            #pragma unroll
            for (int ni = 0; ni < 4; ni++)
                acc[mi][ni] = __builtin_amdgcn_mfma_f32_16x16x32_bf16(af[mi], bf[ni], acc[mi][ni], 0, 0, 0);
        __builtin_amdgcn_s_setprio(0);
        __syncthreads();
    }

    if (EPI == 0) {
        if (seg < 2) {
            #pragma unroll
            for (int mi = 0; mi < 2; mi++) {
                #pragma unroll
                for (int j = 0; j < 4; j++) {
                    const int m = m0 + wr*32 + mi*16 + 4*g + j;
                    const int bb = m >> 11;
                    const int s  = m & 2047;
                    #pragma unroll
                    for (int ni = 0; ni < 4; ni++) {
                        const int n = n0 + wc*64 + ni*16 + r;
                        const int h = n >> 6;
                        const int d = n & 63;
                        outp[((size_t)((bb*NHEADS + h)*SEQ) + s)*HDIM + d] =
                            f2bf((acc[mi][ni][j] + bias[n]) * scale);
                    }
                }
            }
        } else {
            // V^T direct, k-permuted columns: 4 contiguous s stay contiguous
            #pragma unroll
            for (int mi = 0; mi < 2; mi++) {
                const int m  = m0 + wr*32 + mi*16 + 4*g;   // 4-aligned
                const int bb = m >> 11;
                const int s  = m & 2047;
                const int sp = kperm(s);                   // 4-aligned too
                #pragma unroll
                for (int ni = 0; ni < 4; ni++) {
                    const int n = n0 + wc*64 + ni*16 + r;
                    const int h = n >> 6;
                    const int d = n & 63;
                    s4v pk;
                    #pragma unroll
                    for (int j = 0; j < 4; j++)
                        pk[j] = f2bf(acc[mi][ni][j] + bias[n]);
                    *(s4v*)(outp + ((size_t)((bb*NHEADS + h)*HDIM) + d)*SEQ + sp) = pk;
                }
            }
        }
    } else {
        #pragma unroll
        for (int mi = 0; mi < 2; mi++) {
            #pragma unroll
            for (int j = 0; j < 4; j++) {
                const int m = m0 + wr*32 + mi*16 + 4*g + j;
                #pragma unroll
                for (int ni = 0; ni < 4; ni++) {
                    const int n = n0 + wc*64 + ni*16 + r;
                    Fo[(size_t)m*HH + n] = acc[mi][ni][j] + bias[n] + Xres[(size_t)m*HH + n];
                }
            }
        }
    }
}

// ---------------------------------------------------------------------------
// Flash attention, bf16 MFMA, 8 waves / 512 threads, KV-parity split.
// SWAPPED QK^T: mfma(kf, qf) -> lane (r,g) holds P[k][q=r]; k-slot
// permutation matched by V^T kperm layout and permuted fp32 mask LDS.
// Mask applied as MFMA C-INIT. PV A-fragment built in-register (cvt_pk).
// Fixed-max exp2 softmax; scalar per-lane l; parity merge at end.
// LDS 40 KB (K 2x8K, V 2x8K, mask-f32 8K); 128B rows, conflict-free.
// ---------------------------------------------------------------------------
#define NPAIR (SEQ/64)
__global__ __launch_bounds__(512, 4)
void attn_mfma(const short* __restrict__ Q, const short* __restrict__ K,
               const short* __restrict__ VT, const float* __restrict__ mask,
               short* __restrict__ CTX)
{
    // XCD swizzle: 768 blocks = 8 XCDs x 96
    const int wgid = (blockIdx.x & 7) * 96 + (blockIdx.x >> 3);
    const int qt = wgid & 31;
    const int bh = wgid >> 5;
    const int h  = bh % NHEADS;
    const int b  = bh / NHEADS;

    const size_t hb = (size_t)(b * NHEADS + h);
    const short* Qg  = Q  + hb * SEQ * HDIM;
    const short* Kg  = K  + hb * SEQ * HDIM;
    const short* VTg = VT + hb * HDIM * SEQ;   // k-permuted columns

    __shared__ __align__(16) char lds[40960];
    char* Kbase = lds;                    // [2 db][64 k-rows][128B]
    char* Vbase = lds + 16384;            // [2 db][64 d-rows][128B], k-pos order
    float* Mf   = (float*)(lds + 32768);  // [2048] fp32 madd, k-pos order

    const int tid  = threadIdx.x;
    const int w    = tid >> 6;
    const int grp  = w >> 2;
    const int wq   = w & 3;
    const int lane = tid & 63;
    const int g    = lane >> 4;
    const int r    = lane & 15;
    const int q0   = qt * 64;

    const short* qrow = Qg + (size_t)(q0 + wq*16 + r) * HDIM;
    const s8v qf0 = *(const s8v*)(qrow + 8*g);
    const s8v qf1 = *(const s8v*)(qrow + 8*g + 32);

    // one-time mask -> permuted fp32 LDS (512 threads x 4 entries)
    {
        float4 mv = *(const float4*)(mask + b*SEQ + tid*4);
        f4v md;
        md[0] = (mv.x - 1.0f) * (10000.0f * L2E);
        md[1] = (mv.y - 1.0f) * (10000.0f * L2E);
        md[2] = (mv.z - 1.0f) * (10000.0f * L2E);
        md[3] = (mv.w - 1.0f) * (10000.0f * L2E);
        *(f4v*)(Mf + kperm(tid*4)) = md;
    }

    f4v acc[4];
    #pragma unroll
    for (int t = 0; t < 4; t++) acc[t] = (f4v){0.f, 0.f, 0.f, 0.f};
    float lpart = 0.0f;

    const int srow = lane >> 3;
    const int scol = 8 * ((lane & 7) ^ srow);

    #define STAGE(PT, DB) do {                                                 \
        const int pk0 = (PT) * 64;                                             \
        char* kd = Kbase + (DB)*8192 + w*1024;                                 \
        gld16(Kg + (size_t)(pk0 + 8*w + srow)*HDIM + scol, kd);                \
        char* vd = Vbase + (DB)*8192 + w*1024;                                 \
        gld16(VTg + (size_t)(8*w + srow)*SEQ + pk0 + scol, vd);                \
    } while (0)

    STAGE(0, 0);
    __syncthreads();   // staging + mask preload

    for (int pt = 0; pt < NPAIR; ++pt) {
        const int db = pt & 1;
        if (pt + 1 < NPAIR) STAGE(pt + 1, db ^ 1);   // async, drained at barrier

        const char* Kc = Kbase + db*8192 + grp*4096; // 32 k-rows x 128B
        const char* Vc = Vbase + db*8192;            // 64 d-rows x 128B

        // madd C-init: slots (pt*64+grp*32+8g) + 0..3 (z0), +4..7 (z1)
        const float* mrow = Mf + pt*64 + grp*32 + 8*g;
        f4v z0 = *(const f4v*)(mrow);
        f4v z1 = *(const f4v*)(mrow + 4);

        // ---- swapped QK^T: z[jt][i] = S[k] + madd[k], k=4g+i+16jt ----
        __builtin_amdgcn_s_setprio(1);
        {
            const int sw = (r & 7) << 4;
            const char* kb0 = Kc + r * 128;          // jt=0 rows
            const char* kb1 = Kc + (16 + r) * 128;   // jt=1 rows
            s8v ka0 = *(const s8v*)(kb0 + ((16*g)      ^ sw));
            s8v ka1 = *(const s8v*)(kb0 + ((16*g + 64) ^ sw));
            s8v kc0 = *(const s8v*)(kb1 + ((16*g)      ^ sw));
            s8v kc1 = *(const s8v*)(kb1 + ((16*g + 64) ^ sw));
            z0 = __builtin_amdgcn_mfma_f32_16x16x32_bf16(ka0, qf0, z0, 0, 0, 0);
            z0 = __builtin_amdgcn_mfma_f32_16x16x32_bf16(ka1, qf1, z0, 0, 0, 0);
            z1 = __builtin_amdgcn_mfma_f32_16x16x32_bf16(kc0, qf0, z1, 0, 0, 0);
            z1 = __builtin_amdgcn_mfma_f32_16x16x32_bf16(kc1, qf1, z1, 0, 0, 0);
        }
        __builtin_amdgcn_s_setprio(0);

        #pragma unroll
        for (int i = 0; i < 4; i++) {
            z0[i] = EXP2(z0[i]);
            z1[i] = EXP2(z1[i]);
        }
        lpart += ((z0[0] + z0[1]) + (z0[2] + z0[3]))
               + ((z1[0] + z1[1]) + (z1[2] + z1[3]));

        // ---- PV A-fragment fully in-register (slot z = p[z>>2][z&3]) ----
        union { unsigned u[4]; s8v v; } pfu;
        pfu.u[0] = cvt_pk_bf16(z0[0], z0[1]);
        pfu.u[1] = cvt_pk_bf16(z0[2], z0[3]);
        pfu.u[2] = cvt_pk_bf16(z1[0], z1[1]);
        pfu.u[3] = cvt_pk_bf16(z1[2], z1[3]);
        const s8v pf = pfu.v;

        // ---- ctx += P @ V (k-extent 32, permuted positions grp*32+8g..) ----
        __builtin_amdgcn_s_setprio(1);
        #pragma unroll
        for (int t4 = 0; t4 < 4; t4++) {
            const int vrow = 16*t4 + r;
            s8v vf = *(const s8v*)(Vc + vrow*128 + ((16*(4*grp + g)) ^ ((r & 7) << 4)));
            acc[t4] = __builtin_amdgcn_mfma_f32_16x16x32_bf16(pf, vf, acc[t4], 0, 0, 0);
        }
        __builtin_amdgcn_s_setprio(0);

        __syncthreads();   // drains prefetch vmcnt; next pair ready, bufs free
    }

    // ---- reduce l across g-lanes (k-slices of this grp) ----
    lpart += __shfl_xor(lpart, 16);
    lpart += __shfl_xor(lpart, 32);   // all lanes with same r: l for q=wq*16+r

    // ---- merge parity partials (fixed-max => plain adds) ----
    float* lbuf = (float*)(lds + 20480);
    if (grp == 1) {
        float* mb = (float*)(lds + wq*5120 + lane*80);
        *(f4v*)(mb)      = acc[0];
        *(f4v*)(mb + 4)  = acc[1];
        *(f4v*)(mb + 8)  = acc[2];
        *(f4v*)(mb + 12) = acc[3];
        lbuf[wq*64 + lane] = lpart;
    }
    __syncthreads();
    if (grp == 0) {
        const float* mb = (const float*)(lds + wq*5120 + lane*80);
        acc[0] += *(const f4v*)(mb);
        acc[1] += *(const f4v*)(mb + 4);
        acc[2] += *(const f4v*)(mb + 8);
        acc[3] += *(const f4v*)(mb + 12);
        lpart  += lbuf[wq*64 + lane];

        #pragma unroll
        for (int i = 0; i < 4; i++) {
            const float invl = 1.0f / __shfl(lpart, 4*g + i);
            const size_t rowbase = ((size_t)(b*SEQ) + q0 + wq*16 + 4*g + i) * HH + h*HDIM;
            #pragma unroll
            for (int t4 = 0; t4 < 4; t4++)
                CTX[rowbase + 16*t4 + r] = f2bf(acc[t4][i] * invl);
        }
    }
    #undef STAGE
}

// ---------------------------------------------------------------------------
// In-place LayerNorm over rows of 768.
// ---------------------------------------------------------------------------
__global__ __launch_bounds__(256)
void ln_kernel(float* __restrict__ y, const float* __restrict__ gamma,
               const float* __restrict__ beta)
{
    const int row = blockIdx.x;
    float* p = y + (size_t)row * HH;
    const int tid = threadIdx.x;

    float v[3];
    float s = 0.f, ss = 0.f;
    #pragma unroll
    for (int i = 0; i < 3; i++) {
        float x = p[tid + i*256];
        v[i] = x;
        s += x;
        ss += x * x;
    }
    #pragma unroll
    for (int off = 32; off > 0; off >>= 1) {
        s  += __shfl_down(s,  off);
        ss += __shfl_down(ss, off);
    }
    __shared__ float sbuf[4], ssbuf[4];
    __shared__ float mu_s, rstd_s;
    const int wave = tid >> 6;
    if ((tid & 63) == 0) { sbuf[wave] = s; ssbuf[wave] = ss; }
    __syncthreads();
    if (tid == 0) {
        float S  = sbuf[0] + sbuf[1] + sbuf[2] + sbuf[3];
        float SS = ssbuf[0] + ssbuf[1] + ssbuf[2] + ssbuf[3];
        float mu = S * (1.0f / HH);
        float var = SS * (1.0f / HH) - mu * mu;
        mu_s = mu;
        rstd_s = rsqrtf(var + 1e-5f);
    }
    __syncthreads();
    const float mu = mu_s, rstd = rstd_s;
    #pragma unroll
    for (int i = 0; i < 3; i++) {
        const int c = tid + i*256;
        p[c] = (v[i] - mu) * rstd * gamma[c] + beta[c];
    }
}

// ---------------------------------------------------------------------------
extern "C" void kernel_launch(void* const* d_in, const int* in_sizes, int n_in,
                              void* d_out, int out_size, void* d_ws, size_t ws_size,
                              hipStream_t stream)
{
    const float* x     = (const float*)d_in[0];
    const float* mask  = (const float*)d_in[1];
    const float* Wq    = (const float*)d_in[2];
    const float* bq    = (const float*)d_in[3];
    const float* Wk    = (const float*)d_in[4];
    const float* bk    = (const float*)d_in[5];
    const float* Wv    = (const float*)d_in[6];
    const float* bv    = (const float*)d_in[7];
    const float* Wo    = (const float*)d_in[8];
    const float* bo    = (const float*)d_in[9];
    const float* gamma = (const float*)d_in[10];
    const float* beta  = (const float*)d_in[11];

    const size_t PER = (size_t)NB * NHEADS * SEQ * HDIM;
    const size_t WSZ = (size_t)HH * HH;
    short* wsS  = (short*)d_ws;
    short* Xb   = wsS;          // dead after QKV GEMM -> reused as CTXb
    short* Wqb  = wsS + PER;
    short* Wkb  = Wqb + WSZ;
    short* Wvb  = Wkb + WSZ;
    short* Wob  = Wvb + WSZ;
    short* Qb   = Wob + WSZ;
    short* Kb   = Qb + PER;
    short* VTb  = Kb + PER;     // k-permuted V^T written directly by the GEMM
    short* CTXb = Xb;
    float* out  = (float*)d_out;

    cvt_kernel<<<2688, 256, 0, stream>>>(x, Xb, Wq, Wqb, Wk, Wkb, Wv, Wvb, Wo, Wob);

    gemm_mfma<0><<<1152, 256, 0, stream>>>(
        Xb, Wqb, Wkb, Wvb, bq, bk, bv, Qb, Kb, VTb, nullptr, nullptr);

    attn_mfma<<<768, 512, 0, stream>>>(Qb, Kb, VTb, mask, CTXb);

    gemm_mfma<1><<<384, 256, 0, stream>>>(
        CTXb, Wob, nullptr, nullptr, bo, nullptr, nullptr,
        nullptr, nullptr, nullptr, x, out);

    ln_kernel<<<NB*SEQ, 256, 0, stream>>>(out, gamma, beta);
}